// Round 12
// baseline (488.162 us; speedup 1.0000x reference)
//
#include <hip/hip_runtime.h>
#include <stdint.h>

#define F_FRAMES 1296
#define JC 24
#define CH 256
#define NH 8
#define EMAX 120
#define M1 31104
#define N1 1536
#define K1 256
#define M2 22144
#define MREAL 22032
#define K2 1280
#define N2 256

typedef __attribute__((ext_vector_type(8))) short s8v;
typedef __attribute__((ext_vector_type(4))) short s4v;
typedef __attribute__((ext_vector_type(4))) float f4v;

#define GLOBAL_AS __attribute__((address_space(1)))
#define LDS_AS __attribute__((address_space(3)))

__device__ __forceinline__ float b2f(uint16_t u){
  union { float f; uint32_t u; } v; v.u = ((uint32_t)u) << 16; return v.f;
}
__device__ __forceinline__ uint16_t f2b(float f){
  union { float f; uint32_t u; } v; v.f = f;
  uint32_t u = v.u;
  uint32_t r = (u + 0x7fffu + ((u >> 16) & 1u)) >> 16;
  return (uint16_t)r;
}

// ---------------- dtype detection -------------------------------------------
__global__ __launch_bounds__(256) void detect_kernel(const uint16_t* __restrict__ x,
                                                     int* __restrict__ flag){
  __shared__ int cnt;
  if (threadIdx.x == 0) cnt = 0;
  __syncthreads();
  int good = 0;
  for (int i = threadIdx.x; i < 512; i += 256){
    uint16_t v = x[i];
    int e = (v >> 7) & 0xFF;
    good += (e >= 115 && e <= 131) ? 1 : 0;
  }
  atomicAdd(&cnt, good);
  __syncthreads();
  if (threadIdx.x == 0) *flag = (cnt >= 400) ? 1 : 0;
}

// ---------------- convert all float inputs into a bf16 arena ----------------
struct Ptrs { const void* p[21]; };

__constant__ int c_off[22] = {
  0, 5640192, 6033408, 6033472, 6033728, 6033984, 6427200, 6427264, 6427520,
  6427776, 6820992, 6821056, 6821312, 6821568, 7214784, 7214848, 7215104,
  7215360, 7543040, 7543296, 7543552, 7543808};

__global__ __launch_bounds__(256) void convert_kernel(Ptrs ptrs,
        const int* __restrict__ flag, uint16_t* __restrict__ arena){
  long base = ((long)blockIdx.x * 256 + threadIdx.x) * 8;
  if (base >= 7543808L) return;
  int seg = 0;
  while (c_off[seg + 1] <= base) seg++;
  long loc = base - c_off[seg];
  if (*flag){
    *(s8v*)(arena + base) = *(const s8v*)((const uint16_t*)ptrs.p[seg] + loc);
  } else {
    const float* s = (const float*)ptrs.p[seg] + loc;
    f4v a = *(const f4v*)s;
    f4v b = *(const f4v*)(s + 4);
    s8v o;
    #pragma unroll
    for (int u = 0; u < 4; u++){ o[u] = (short)f2b(a[u]); o[4+u] = (short)f2b(b[u]); }
    *(s8v*)(arena + base) = o;
  }
}

// ---------------- prep ---------------------------------------------------------
__global__ __launch_bounds__(256) void prep_kernel(const uint16_t* __restrict__ x,
                     uint16_t* __restrict__ xc0, uint16_t* __restrict__ y){
  long i = (long)blockIdx.x * 256 + threadIdx.x;
  const long n1 = (long)F_FRAMES * JC * CH;
  const long n2 = (long)MREAL * CH;
  const long n3 = (long)(M2 - MREAL) * K2;
  if (i < n1){
    long f = i / (JC*CH); long r = i % (JC*CH);
    int j = (int)(r >> 8); int c = (int)(r & 255);
    uint16_t v = 0;
    if (j < 17) v = x[(f*17 + j)*CH + c];
    xc0[i] = v;
  } else if (i < n1 + n2){
    long i2 = i - n1;
    long row = i2 >> 8; int c = (int)(i2 & 255);
    y[row*K2 + c] = x[i2];
  } else if (i < n1 + n2 + n3){
    long i3 = i - n1 - n2;
    long row = MREAL + i3 / K2; int c = (int)(i3 % K2);
    y[row*K2 + c] = 0;
  }
}

// ---------------- build per-src edge lists (once per call) -------------------
__global__ __launch_bounds__(64) void build_elist(const int* __restrict__ eskel,
        const int* __restrict__ ecay, int* __restrict__ out){
  int t = threadIdx.x;
  int g = t >> 5, j = t & 31;
  if (j < 24){
    const int* ed = g ? ecay : eskel;
    int E = g ? 120 : 49;
    int c = 0;
    for (int e = 0; e < E; e++)
      if (ed[e] == j){ out[48 + (g*24 + j)*8 + c] = e; c++; }
    out[g*24 + j] = c;
  }
}

// ---------------- wv_copy: gather v-rows of all 4 W's into [512][256] --------
struct WPtrs { const uint16_t* w[4]; };
__global__ __launch_bounds__(256) void wv_copy(WPtrs wp, uint16_t* __restrict__ wv){
  int g = blockIdx.x * 256 + threadIdx.x;
  int L = g >> 14;
  int loc = g & 16383;
  int row = loc >> 5;
  int col = (loc & 31) * 8;
  int wrow = (row >> 6) * 192 + 128 + (row & 63);
  *(s8v*)(wv + ((long)L*512 + row)*256 + col) =
      *(const s8v*)(wp.w[L] + (long)wrow*256 + col);
}

// ---------------- GEMM (final projection): XCD swizzle + T2 swizzle ----------
template<int OUT_F32>
__global__ __launch_bounds__(256) void gemm_bt(const uint16_t* __restrict__ A,
        const uint16_t* __restrict__ B, void* __restrict__ Cv,
        int M, int N, int K, int nbn){
  __shared__ uint16_t As[128*64];
  __shared__ uint16_t Bs[128*64];
  int t = threadIdx.x;
  int lane = t & 63, w = t >> 6;
  int wr = (w >> 1) * 64, wc = (w & 1) * 64;

  int total = gridDim.x;
  int q = total >> 3, r = total & 7;
  int orig = blockIdx.x;
  int xcd = orig & 7, loc = orig >> 3;
  int wgid = (xcd < r ? xcd*(q+1) : r*(q+1) + (xcd-r)*q) + loc;
  long bm = (long)(wgid / nbn) * 128;
  long bn = (long)(wgid % nbn) * 128;

  f4v acc[4][4];
  #pragma unroll
  for (int i=0;i<4;i++){
    #pragma unroll
    for (int jq=0;jq<4;jq++) acc[i][jq] = (f4v){0.f,0.f,0.f,0.f};
  }
  const int nk = K >> 6;
  for (int kt = 0; kt < nk; ++kt){
    const uint16_t* Ag = A + bm * K + kt*64;
    const uint16_t* Bg = B + bn * K + kt*64;
    #pragma unroll
    for (int i=0;i<4;i++){
      int flat = i*256 + t;
      int row = flat >> 3, col = ((flat ^ row) & 7) << 3;
      __builtin_amdgcn_global_load_lds(
        (const GLOBAL_AS void*)(Ag + (long)row*K + col),
        (LDS_AS void*)(As + flat*8), 16, 0, 0);
    }
    #pragma unroll
    for (int i=0;i<4;i++){
      int flat = i*256 + t;
      int row = flat >> 3, col = ((flat ^ row) & 7) << 3;
      __builtin_amdgcn_global_load_lds(
        (const GLOBAL_AS void*)(Bg + (long)row*K + col),
        (LDS_AS void*)(Bs + flat*8), 16, 0, 0);
    }
    __syncthreads();
    #pragma unroll
    for (int kk=0; kk<2; ++kk){
      s8v af[4], bfr[4];
      int ch = kk*4 + (lane>>4);
      #pragma unroll
      for (int mi=0;mi<4;mi++){
        int row = wr + mi*16 + (lane&15);
        af[mi] = *(const s8v*)(As + row*64 + ((ch ^ (row&7))<<3));
      }
      #pragma unroll
      for (int ni=0;ni<4;ni++){
        int row = wc + ni*16 + (lane&15);
        bfr[ni] = *(const s8v*)(Bs + row*64 + ((ch ^ (row&7))<<3));
      }
      #pragma unroll
      for (int mi=0;mi<4;mi++){
        #pragma unroll
        for (int ni=0;ni<4;ni++)
          acc[mi][ni] = __builtin_amdgcn_mfma_f32_16x16x32_bf16(af[mi], bfr[ni], acc[mi][ni], 0,0,0);
      }
    }
    __syncthreads();
  }
  #pragma unroll
  for (int mi=0;mi<4;mi++){
    #pragma unroll
    for (int ni=0;ni<4;ni++){
      long col = bn + wc + ni*16 + (lane & 15);
      #pragma unroll
      for (int r2=0;r2<4;r2++){
        long row = bm + wr + mi*16 + (lane>>4)*4 + r2;
        if (OUT_F32) ((float*)Cv)[row*N + col] = acc[mi][ni][r2];
        else ((uint16_t*)Cv)[row*N + col] = f2b(acc[mi][ni][r2]);
      }
    }
  }
}

// ---------------- qk GEMM + fused logits (unchanged, proven) ------------------
template<int E>
__global__ __launch_bounds__(512) void qk_logit(
    const uint16_t* __restrict__ xc_in, const uint16_t* __restrict__ W,
    const uint16_t* __restrict__ aw, const int* __restrict__ edges,
    float* __restrict__ sexg)
{
  __shared__ uint16_t AB[14336];
  __shared__ float awf[64];
  __shared__ int esrc[EMAX], edst[EMAX];

  int t = threadIdx.x;
  int lane = t & 63, w = t >> 6;
  int wr = w >> 2, wc = w & 3;

  int orig = blockIdx.x;
  int wgid = (orig & 7) * 324 + (orig >> 3);
  int mp = wgid >> 3;
  int h  = wgid & 7;

  if (t < E){ esrc[t] = edges[t]; edst[t] = edges[E+t]; }
  if (t >= 128 && t < 192) awf[t-128] = b2f(aw[t-128]);

  uint16_t* As = AB;
  uint16_t* Bs = AB + 6144;
  const uint16_t* Ag0 = xc_in + (long)mp*96*256;
  const uint16_t* Bg0 = W + (long)h*192*256;

  f4v acc[3][2];
  #pragma unroll
  for (int i=0;i<3;i++){
    acc[i][0] = (f4v){0.f,0.f,0.f,0.f};
    acc[i][1] = (f4v){0.f,0.f,0.f,0.f};
  }

  for (int kt = 0; kt < 4; ++kt){
    {
      int g = t;
      int row = g >> 3, col = ((g ^ row) & 7) << 3;
      __builtin_amdgcn_global_load_lds(
        (const GLOBAL_AS void*)(Ag0 + (long)row*256 + kt*64 + col),
        (LDS_AS void*)(As + g*8), 16, 0, 0);
      if (t < 256){
        g = 512 + t;
        row = g >> 3; col = ((g ^ row) & 7) << 3;
        __builtin_amdgcn_global_load_lds(
          (const GLOBAL_AS void*)(Ag0 + (long)row*256 + kt*64 + col),
          (LDS_AS void*)(As + g*8), 16, 0, 0);
      }
    }
    #pragma unroll
    for (int i=0;i<2;i++){
      int g = i*512 + t;
      int row = g >> 3, col = ((g ^ row) & 7) << 3;
      __builtin_amdgcn_global_load_lds(
        (const GLOBAL_AS void*)(Bg0 + (long)row*256 + kt*64 + col),
        (LDS_AS void*)(Bs + g*8), 16, 0, 0);
    }
    __syncthreads();
    #pragma unroll
    for (int kk=0; kk<2; ++kk){
      s8v af[3], bfr[2];
      int ch = kk*4 + (lane>>4);
      #pragma unroll
      for (int mi=0;mi<3;mi++){
        int row = wr*48 + mi*16 + (lane&15);
        af[mi] = *(const s8v*)(As + row*64 + ((ch ^ (row&7))<<3));
      }
      #pragma unroll
      for (int ni=0;ni<2;ni++){
        int row = wc*32 + ni*16 + (lane&15);
        bfr[ni] = *(const s8v*)(Bs + row*64 + ((ch ^ (row&7))<<3));
      }
      #pragma unroll
      for (int mi=0;mi<3;mi++){
        #pragma unroll
        for (int ni=0;ni<2;ni++)
          acc[mi][ni] = __builtin_amdgcn_mfma_f32_16x16x32_bf16(af[mi], bfr[ni], acc[mi][ni], 0,0,0);
      }
    }
    __syncthreads();
  }

  uint16_t* qs = AB;
  #pragma unroll
  for (int mi=0;mi<3;mi++){
    #pragma unroll
    for (int ni=0;ni<2;ni++){
      int col = wc*32 + ni*16 + (lane & 15);
      int ch = col >> 3;
      #pragma unroll
      for (int r2=0;r2<4;r2++){
        int row = wr*48 + mi*16 + (lane>>4)*4 + r2;
        int pch = (ch & 8) | ((ch ^ row) & 7);
        qs[row*128 + pch*8 + (col & 7)] = f2b(acc[mi][ni][r2]);
      }
    }
  }
  __syncthreads();

  float aln2[8];
  {
    int ln2i = t & 7;
    #pragma unroll
    for (int u=0;u<8;u++)
      aln2[u] = awf[ln2i*8 + u] * 0.69314718056f;
  }
  int ln = t & 7;
  for (int e0 = t >> 3; e0 < E; e0 += 64){
    int ns = esrc[e0], nd = edst[e0];
    const uint16_t* qp = qs + ns*128 + ((ln ^ ns) & 7)*8;
    const uint16_t* kp = qs + nd*128 + (8 | ((ln ^ nd) & 7))*8;
    #pragma unroll
    for (int fl=0; fl<4; ++fl){
      s8v qv = *(const s8v*)(qp + fl*3072);
      s8v kv = *(const s8v*)(kp + fl*3072);
      float s = 0.f;
      #pragma unroll
      for (int u=0;u<8;u++){
        float xv = b2f((uint16_t)qv[u]) + b2f((uint16_t)kv[u]);
        float e2 = __builtin_amdgcn_exp2f(xv * 1.44269504f);
        float lg = __builtin_amdgcn_logf(1.f + e2);
        s = lg * aln2[u] + s;
      }
      s += __shfl_xor(s, 1, 64);
      s += __shfl_xor(s, 2, 64);
      s += __shfl_xor(s, 4, 64);
      if (ln == 0)
        sexg[((long)mp*4 + fl)*(E*NH) + e0*NH + h] = s;
    }
  }
}

// ---------------- gat_fused: v-GEMM (MFMA) + softmax + aggregate + LN --------
// One frame per block, 256 thr = 4 waves. vout never touches HBM.
template<int E>
__global__ __launch_bounds__(256) void gat_fused(
    const uint16_t* __restrict__ xc, const uint16_t* __restrict__ wvL,
    const int* __restrict__ edges, const float* __restrict__ sexg,
    const int* __restrict__ elg,
    const uint16_t* __restrict__ gw, const uint16_t* __restrict__ bw,
    uint16_t* __restrict__ xc_out, uint16_t* __restrict__ y,
    int ycol, int graph)
{
  __shared__ uint16_t As[32*256];      // 16 KB; rows 24-31 unwritten (dropped)
  __shared__ uint16_t vs[24*512];      // 24.5 KB, granule-swizzled v output
  __shared__ float sexs[EMAX*NH];
  __shared__ float smax[NH];
  __shared__ int edst[EMAX];
  __shared__ uint16_t glb[2*CH];

  int f = blockIdx.x;
  int t = threadIdx.x;
  int lane = t & 63, w = t >> 6;
  const int EN = E * NH;

  // stage A = xc[f][24][256], 16B-granule XOR swizzle (inverse-swizzled source)
  const uint16_t* xf = xc + (long)f*JC*CH;
  #pragma unroll
  for (int i=0;i<3;i++){
    int g = i*256 + t;                 // 0..767
    int r = g >> 5, c = g & 31;
    int cs = (c & 24) | ((c ^ r) & 7);
    __builtin_amdgcn_global_load_lds(
      (const GLOBAL_AS void*)(xf + r*256 + cs*8),
      (LDS_AS void*)(As + g*8), 16, 0, 0);
  }
  if (t < E) edst[t] = edges[E + t];
  if (t < (EN >> 2)) ((f4v*)sexs)[t] = ((const f4v*)(sexg + (long)f*EN))[t];
  glb[t] = gw[t]; glb[256 + t] = bw[t];
  __syncthreads();

  // MFMA: C[32][512] = A[32][256] * Wv^T; wave w owns cols w*128..w*128+127
  f4v acc[2][8];
  #pragma unroll
  for (int mt=0;mt<2;mt++){
    #pragma unroll
    for (int nt=0;nt<8;nt++) acc[mt][nt] = (f4v){0.f,0.f,0.f,0.f};
  }
  const uint16_t* Bb = wvL + ((long)(w*128 + (lane & 15)))*256 + ((lane>>4)*8);
  #pragma unroll
  for (int ks=0; ks<8; ++ks){
    int c0 = ks*4 + (lane>>4);
    int r0 = lane & 15;
    int sl = (c0 & 24) | ((c0 ^ r0) & 7);
    s8v a0 = *(const s8v*)(As + r0*256 + sl*8);
    s8v a1 = *(const s8v*)(As + (16 + r0)*256 + sl*8);
    #pragma unroll
    for (int nt=0; nt<8; ++nt){
      s8v b = *(const s8v*)(Bb + (long)nt*16*256 + ks*32);
      acc[0][nt] = __builtin_amdgcn_mfma_f32_16x16x32_bf16(a0, b, acc[0][nt], 0,0,0);
      acc[1][nt] = __builtin_amdgcn_mfma_f32_16x16x32_bf16(a1, b, acc[1][nt], 0,0,0);
    }
  }
  // epilogue: C rows<24 -> vs (granule swizzle: sl = (g&56) | ((g&7)^(g>>3)))
  #pragma unroll
  for (int nt=0; nt<8; ++nt){
    int col = w*128 + nt*16 + (lane & 15);
    int g = col >> 3;
    int sl = (g & 56) | ((g & 7) ^ (g >> 3));
    int cbase = sl*8 + (col & 7);
    #pragma unroll
    for (int r2=0; r2<4; ++r2){
      int row0 = (lane>>4)*4 + r2;
      vs[row0*512 + cbase] = f2b(acc[0][nt][r2]);
      int row1 = 16 + row0;
      if (row1 < 24) vs[row1*512 + cbase] = f2b(acc[1][nt][r2]);
    }
  }
  __syncthreads();

  // per-head max
  if (t < 64){
    int h = t & 7;
    float m = -3.4e38f;
    for (int e = t >> 3; e < E; e += 8) m = fmaxf(m, sexs[e*8 + h]);
    m = fmaxf(m, __shfl_xor(m, 8, 64));
    m = fmaxf(m, __shfl_xor(m, 16, 64));
    m = fmaxf(m, __shfl_xor(m, 32, 64));
    if (t < 8) smax[t] = m;
  }
  __syncthreads();

  // per (j,h): softmax + aggregate + residual + LN
  if (t < JC*NH){
    int j = t >> 3, h = t & 7;
    int deg = elg[graph*24 + j];
    const int* lst = elg + 48 + (graph*24 + j)*8;
    float mh = smax[h];
    float ex[8];
    float sig = 1e-10f;
    int el[8];
    #pragma unroll
    for (int i=0;i<8;i++){
      float v = 0.f; int e = 0;
      if (i < deg){ e = lst[i]; v = __builtin_amdgcn_exp2f((sexs[e*8+h] - mh) * 1.44269504f); }
      el[i] = e; ex[i] = v; sig += v;
    }
    float inv = 1.f / sig;
    float acc5[32];
    #pragma unroll
    for (int d=0;d<32;d++) acc5[d] = 0.f;
    #pragma unroll
    for (int i=0;i<8;i++){
      if (i < deg){
        float wgt = ex[i] * inv;
        int r = edst[el[i]];
        #pragma unroll
        for (int c=0;c<4;c++){
          int sl = h*8 + (((4 + c) ^ h) & 7);   // g = h*8+4+c, g>>3 = h
          s8v v = *(const s8v*)(vs + r*512 + sl*8);
          #pragma unroll
          for (int u=0;u<8;u++) acc5[c*8+u] += wgt * b2f((uint16_t)v[u]);
        }
      }
    }

    float pre[32]; float sum = 0.f, sq = 0.f;
    #pragma unroll
    for (int c=0;c<4;c++){
      int sl1 = h*8 + ((c ^ h) & 7);            // v1: g = h*8+c
      s8v v1 = *(const s8v*)(vs + j*512 + sl1*8);
      int ca = h*4 + c;                          // xc: granule in As row j
      int sla = (ca & 24) | ((ca ^ j) & 7);
      s8v xv = *(const s8v*)(As + j*256 + sla*8);
      #pragma unroll
      for (int u=0;u<8;u++){
        float p = b2f((uint16_t)xv[u]) + 0.2f*b2f((uint16_t)v1[u]) + 0.8f*acc5[c*8+u];
        pre[c*8+u] = p; sum += p; sq += p*p;
      }
    }
    #pragma unroll
    for (int m=1;m<8;m<<=1){ sum += __shfl_xor(sum, m, 64); sq += __shfl_xor(sq, m, 64); }
    float mean = sum * (1.f/256.f);
    float var = sq * (1.f/256.f) - mean*mean;
    float rstd = rsqrtf(var + 1e-5f);
    uint16_t* xo = xc_out + (long)f*JC*CH + t*32;
    uint16_t* yo = (j < 17) ? (y + (long)(f*17 + j)*K2 + ycol + h*32) : (uint16_t*)0;
    #pragma unroll
    for (int d0=0; d0<32; d0+=8){
      s8v ov;
      #pragma unroll
      for (int u=0;u<8;u++){
        int c = h*32 + d0 + u;
        float val = (pre[d0+u]-mean)*rstd*b2f(glb[c]) + b2f(glb[256+c]);
        ov[u] = (short)f2b(val);
      }
      *(s8v*)(xo + d0) = ov;
      if (yo) *(s8v*)(yo + d0) = ov;
    }
  }
}

// ---------------- final bias + LN --------------------------------------------
__global__ __launch_bounds__(256) void final_ln(const float* __restrict__ pre,
    const uint16_t* __restrict__ pb, const uint16_t* __restrict__ gp,
    const uint16_t* __restrict__ bp, const int* __restrict__ flag,
    void* __restrict__ out){
  int row = blockIdx.x*4 + (threadIdx.x>>6);
  int lane = threadIdx.x & 63;
  const float* p = pre + (long)row*CH + lane*4;
  f4v pv = *(const f4v*)p;
  float v[4]; float sum = 0.f, sq = 0.f;
  #pragma unroll
  for (int i=0;i<4;i++){ int c = lane*4+i; v[i] = pv[i] + b2f(pb[c]); sum += v[i]; sq += v[i]*v[i]; }
  #pragma unroll
  for (int m=1;m<64;m<<=1){ sum += __shfl_xor(sum, m, 64); sq += __shfl_xor(sq, m, 64); }
  float mean = sum * (1.f/256.f);
  float var = sq * (1.f/256.f) - mean*mean;
  float rstd = rsqrtf(var + 1e-5f);
  float o[4];
  #pragma unroll
  for (int i=0;i<4;i++){
    int c = lane*4+i;
    o[i] = (v[i]-mean)*rstd*b2f(gp[c]) + b2f(bp[c]);
  }
  if (*flag){
    s4v ov;
    #pragma unroll
    for (int i=0;i<4;i++) ov[i] = (short)f2b(o[i]);
    *(s4v*)((uint16_t*)out + (long)row*CH + lane*4) = ov;
  } else {
    f4v ov;
    #pragma unroll
    for (int i=0;i<4;i++) ov[i] = o[i];
    *(f4v*)((float*)out + (long)row*CH + lane*4) = ov;
  }
}

// ---------------- launch ------------------------------------------------------
extern "C" void kernel_launch(void* const* d_in, const int* in_sizes, int n_in,
                              void* d_out, int out_size, void* d_ws, size_t ws_size,
                              hipStream_t stream){
  const int* eskel = (const int*)d_in[21];
  const int* ecay  = (const int*)d_in[22];

  char* ws = (char*)d_ws;
  const size_t QKV_B  = (size_t)M1 * N1 * 2;
  const size_t XC_B   = (size_t)M1 * CH * 2;
  const size_t Y_B    = (size_t)M2 * K2 * 2;
  const size_t ARENA_OFF = QKV_B + 2*XC_B + Y_B;
  const size_t ARENA_B = 7543808L * 2;
  float*    pre  = (float*)ws;
  uint16_t* xcA = (uint16_t*)(ws + QKV_B);
  uint16_t* xcB = (uint16_t*)(ws + QKV_B + XC_B);
  uint16_t* y   = (uint16_t*)(ws + QKV_B + 2*XC_B);
  uint16_t* arena = (uint16_t*)(ws + ARENA_OFF);
  int*      flag  = (int*)(ws + ARENA_OFF + ARENA_B);
  int*      elg   = flag + 16;
  uint16_t* wv    = (uint16_t*)(ws + ARENA_OFF + ARENA_B + 4096);
  float*    sexg  = (float*)arena;

  const uint16_t* x_bf = arena;
  const uint16_t* wq[4] = {arena + 5640192, arena + 6033984, arena + 6427776, arena + 6821568};
  const uint16_t* aw[4] = {arena + 6033408, arena + 6427200, arena + 6820992, arena + 7214784};
  const uint16_t* gg[4] = {arena + 6033472, arena + 6427264, arena + 6821056, arena + 7214848};
  const uint16_t* bb[4] = {arena + 6033728, arena + 6427520, arena + 6821312, arena + 7215104};
  const uint16_t* pw = arena + 7215360;
  const uint16_t* pb = arena + 7543040;
  const uint16_t* gp = arena + 7543296;
  const uint16_t* bp = arena + 7543552;

  detect_kernel<<<1, 256, 0, stream>>>((const uint16_t*)d_in[0], flag);

  Ptrs ptrs;
  for (int i = 0; i < 21; i++) ptrs.p[i] = d_in[i];
  convert_kernel<<<3684, 256, 0, stream>>>(ptrs, flag, arena);

  prep_kernel<<<53696, 256, 0, stream>>>(x_bf, xcA, y);
  build_elist<<<1, 64, 0, stream>>>(eskel, ecay, elg);

  WPtrs wp = {{wq[0], wq[1], wq[2], wq[3]}};
  wv_copy<<<256, 256, 0, stream>>>(wp, wv);

  uint16_t* xcs[2] = {xcA, xcB};
  for (int L = 0; L < 4; ++L){
    const int* ed = (L & 1) ? ecay : eskel;
    if (L & 1) qk_logit<120><<<2592, 512, 0, stream>>>(xcs[L & 1], wq[L], aw[L], ed, sexg);
    else       qk_logit<49> <<<2592, 512, 0, stream>>>(xcs[L & 1], wq[L], aw[L], ed, sexg);
    if (L & 1) gat_fused<120><<<F_FRAMES, 256, 0, stream>>>(xcs[L & 1], wv + (long)L*512*256,
                         ed, sexg, elg, gg[L], bb[L], xcs[(L + 1) & 1], y, (L + 1) * 256, 1);
    else       gat_fused<49> <<<F_FRAMES, 256, 0, stream>>>(xcs[L & 1], wv + (long)L*512*256,
                         ed, sexg, elg, gg[L], bb[L], xcs[(L + 1) & 1], y, (L + 1) * 256, 0);
  }
  gemm_bt<1><<<346, 256, 0, stream>>>(y, pw, pre, M2, N2, K2, 2);
  final_ln<<<5508, 256, 0, stream>>>(pre, pb, gp, bp, flag, d_out);
}

// Round 13
// 402.702 us; speedup vs baseline: 1.2122x; 1.2122x over previous
//
#include <hip/hip_runtime.h>
#include <stdint.h>

#define F_FRAMES 1296
#define JC 24
#define CH 256
#define NH 8
#define EMAX 120
#define M1 31104
#define N1 1536
#define K1 256
#define M2 22144
#define MREAL 22032
#define K2 1280
#define N2 256

typedef __attribute__((ext_vector_type(8))) short s8v;
typedef __attribute__((ext_vector_type(4))) short s4v;
typedef __attribute__((ext_vector_type(4))) float f4v;

#define GLOBAL_AS __attribute__((address_space(1)))
#define LDS_AS __attribute__((address_space(3)))

__device__ __forceinline__ float b2f(uint16_t u){
  union { float f; uint32_t u; } v; v.u = ((uint32_t)u) << 16; return v.f;
}
__device__ __forceinline__ uint16_t f2b(float f){
  union { float f; uint32_t u; } v; v.f = f;
  uint32_t u = v.u;
  uint32_t r = (u + 0x7fffu + ((u >> 16) & 1u)) >> 16;
  return (uint16_t)r;
}

// ---------------- dtype detection -------------------------------------------
__global__ __launch_bounds__(256) void detect_kernel(const uint16_t* __restrict__ x,
                                                     int* __restrict__ flag){
  __shared__ int cnt;
  if (threadIdx.x == 0) cnt = 0;
  __syncthreads();
  int good = 0;
  for (int i = threadIdx.x; i < 512; i += 256){
    uint16_t v = x[i];
    int e = (v >> 7) & 0xFF;
    good += (e >= 115 && e <= 131) ? 1 : 0;
  }
  atomicAdd(&cnt, good);
  __syncthreads();
  if (threadIdx.x == 0) *flag = (cnt >= 400) ? 1 : 0;
}

// ---------------- convert all float inputs into a bf16 arena ----------------
struct Ptrs { const void* p[21]; };

__constant__ int c_off[22] = {
  0, 5640192, 6033408, 6033472, 6033728, 6033984, 6427200, 6427264, 6427520,
  6427776, 6820992, 6821056, 6821312, 6821568, 7214784, 7214848, 7215104,
  7215360, 7543040, 7543296, 7543552, 7543808};

__global__ __launch_bounds__(256) void convert_kernel(Ptrs ptrs,
        const int* __restrict__ flag, uint16_t* __restrict__ arena){
  long base = ((long)blockIdx.x * 256 + threadIdx.x) * 8;
  if (base >= 7543808L) return;
  int seg = 0;
  while (c_off[seg + 1] <= base) seg++;
  long loc = base - c_off[seg];
  if (*flag){
    *(s8v*)(arena + base) = *(const s8v*)((const uint16_t*)ptrs.p[seg] + loc);
  } else {
    const float* s = (const float*)ptrs.p[seg] + loc;
    f4v a = *(const f4v*)s;
    f4v b = *(const f4v*)(s + 4);
    s8v o;
    #pragma unroll
    for (int u = 0; u < 4; u++){ o[u] = (short)f2b(a[u]); o[4+u] = (short)f2b(b[u]); }
    *(s8v*)(arena + base) = o;
  }
}

// ---------------- prep ---------------------------------------------------------
__global__ __launch_bounds__(256) void prep_kernel(const uint16_t* __restrict__ x,
                     uint16_t* __restrict__ xc0, uint16_t* __restrict__ y){
  long i = (long)blockIdx.x * 256 + threadIdx.x;
  const long n1 = (long)F_FRAMES * JC * CH;
  const long n2 = (long)MREAL * CH;
  const long n3 = (long)(M2 - MREAL) * K2;
  if (i < n1){
    long f = i / (JC*CH); long r = i % (JC*CH);
    int j = (int)(r >> 8); int c = (int)(r & 255);
    uint16_t v = 0;
    if (j < 17) v = x[(f*17 + j)*CH + c];
    xc0[i] = v;
  } else if (i < n1 + n2){
    long i2 = i - n1;
    long row = i2 >> 8; int c = (int)(i2 & 255);
    y[row*K2 + c] = x[i2];
  } else if (i < n1 + n2 + n3){
    long i3 = i - n1 - n2;
    long row = MREAL + i3 / K2; int c = (int)(i3 % K2);
    y[row*K2 + c] = 0;
  }
}

// ---------------- build per-src edge lists (once per call) -------------------
__global__ __launch_bounds__(64) void build_elist(const int* __restrict__ eskel,
        const int* __restrict__ ecay, int* __restrict__ out){
  int t = threadIdx.x;
  int g = t >> 5, j = t & 31;
  if (j < 24){
    const int* ed = g ? ecay : eskel;
    int E = g ? 120 : 49;
    int c = 0;
    for (int e = 0; e < E; e++)
      if (ed[e] == j){ out[48 + (g*24 + j)*8 + c] = e; c++; }
    out[g*24 + j] = c;
  }
}

// ---------------- wv_copy: gather v-rows of all 4 W's into [512][256] --------
struct WPtrs { const uint16_t* w[4]; };
__global__ __launch_bounds__(256) void wv_copy(WPtrs wp, uint16_t* __restrict__ wv){
  int g = blockIdx.x * 256 + threadIdx.x;
  int L = g >> 14;
  int loc = g & 16383;
  int row = loc >> 5;
  int col = (loc & 31) * 8;
  int wrow = (row >> 6) * 192 + 128 + (row & 63);
  *(s8v*)(wv + ((long)L*512 + row)*256 + col) =
      *(const s8v*)(wp.w[L] + (long)wrow*256 + col);
}

// ---------------- GEMM (v path): XCD swizzle + T2 chunk-XOR LDS swizzle -------
template<int OUT_F32>
__global__ __launch_bounds__(256) void gemm_bt(const uint16_t* __restrict__ A,
        const uint16_t* __restrict__ B, void* __restrict__ Cv,
        int M, int N, int K, int nbn){
  __shared__ uint16_t As[128*64];
  __shared__ uint16_t Bs[128*64];
  int t = threadIdx.x;
  int lane = t & 63, w = t >> 6;
  int wr = (w >> 1) * 64, wc = (w & 1) * 64;

  int total = gridDim.x;
  int q = total >> 3, r = total & 7;
  int orig = blockIdx.x;
  int xcd = orig & 7, loc = orig >> 3;
  int wgid = (xcd < r ? xcd*(q+1) : r*(q+1) + (xcd-r)*q) + loc;
  long bm = (long)(wgid / nbn) * 128;
  long bn = (long)(wgid % nbn) * 128;

  f4v acc[4][4];
  #pragma unroll
  for (int i=0;i<4;i++){
    #pragma unroll
    for (int jq=0;jq<4;jq++) acc[i][jq] = (f4v){0.f,0.f,0.f,0.f};
  }
  const int nk = K >> 6;
  for (int kt = 0; kt < nk; ++kt){
    const uint16_t* Ag = A + bm * K + kt*64;
    const uint16_t* Bg = B + bn * K + kt*64;
    #pragma unroll
    for (int i=0;i<4;i++){
      int flat = i*256 + t;
      int row = flat >> 3, col = ((flat ^ row) & 7) << 3;
      __builtin_amdgcn_global_load_lds(
        (const GLOBAL_AS void*)(Ag + (long)row*K + col),
        (LDS_AS void*)(As + flat*8), 16, 0, 0);
    }
    #pragma unroll
    for (int i=0;i<4;i++){
      int flat = i*256 + t;
      int row = flat >> 3, col = ((flat ^ row) & 7) << 3;
      __builtin_amdgcn_global_load_lds(
        (const GLOBAL_AS void*)(Bg + (long)row*K + col),
        (LDS_AS void*)(Bs + flat*8), 16, 0, 0);
    }
    __syncthreads();
    #pragma unroll
    for (int kk=0; kk<2; ++kk){
      s8v af[4], bfr[4];
      int ch = kk*4 + (lane>>4);
      #pragma unroll
      for (int mi=0;mi<4;mi++){
        int row = wr + mi*16 + (lane&15);
        af[mi] = *(const s8v*)(As + row*64 + ((ch ^ (row&7))<<3));
      }
      #pragma unroll
      for (int ni=0;ni<4;ni++){
        int row = wc + ni*16 + (lane&15);
        bfr[ni] = *(const s8v*)(Bs + row*64 + ((ch ^ (row&7))<<3));
      }
      #pragma unroll
      for (int mi=0;mi<4;mi++){
        #pragma unroll
        for (int ni=0;ni<4;ni++)
          acc[mi][ni] = __builtin_amdgcn_mfma_f32_16x16x32_bf16(af[mi], bfr[ni], acc[mi][ni], 0,0,0);
      }
    }
    __syncthreads();
  }
  #pragma unroll
  for (int mi=0;mi<4;mi++){
    #pragma unroll
    for (int ni=0;ni<4;ni++){
      long col = bn + wc + ni*16 + (lane & 15);
      #pragma unroll
      for (int r2=0;r2<4;r2++){
        long row = bm + wr + mi*16 + (lane>>4)*4 + r2;
        if (OUT_F32) ((float*)Cv)[row*N + col] = acc[mi][ni][r2];
        else ((uint16_t*)Cv)[row*N + col] = f2b(acc[mi][ni][r2]);
      }
    }
  }
}

// ---------------- qk GEMM + fused logits (q,k pre-scaled by log2e) ------------
template<int E>
__global__ __launch_bounds__(512) void qk_logit(
    const uint16_t* __restrict__ xc_in, const uint16_t* __restrict__ W,
    const uint16_t* __restrict__ aw, const int* __restrict__ edges,
    float* __restrict__ sexg)
{
  __shared__ uint16_t AB[14336];
  __shared__ float awf[64];
  __shared__ int esrc[EMAX], edst[EMAX];

  int t = threadIdx.x;
  int lane = t & 63, w = t >> 6;
  int wr = w >> 2, wc = w & 3;

  int orig = blockIdx.x;
  int wgid = (orig & 7) * 324 + (orig >> 3);
  int mp = wgid >> 3;
  int h  = wgid & 7;

  if (t < E){ esrc[t] = edges[t]; edst[t] = edges[E+t]; }
  if (t >= 128 && t < 192) awf[t-128] = b2f(aw[t-128]);

  uint16_t* As = AB;
  uint16_t* Bs = AB + 6144;
  const uint16_t* Ag0 = xc_in + (long)mp*96*256;
  const uint16_t* Bg0 = W + (long)h*192*256;

  f4v acc[3][2];
  #pragma unroll
  for (int i=0;i<3;i++){
    acc[i][0] = (f4v){0.f,0.f,0.f,0.f};
    acc[i][1] = (f4v){0.f,0.f,0.f,0.f};
  }

  for (int kt = 0; kt < 4; ++kt){
    {
      int g = t;
      int row = g >> 3, col = ((g ^ row) & 7) << 3;
      __builtin_amdgcn_global_load_lds(
        (const GLOBAL_AS void*)(Ag0 + (long)row*256 + kt*64 + col),
        (LDS_AS void*)(As + g*8), 16, 0, 0);
      if (t < 256){
        g = 512 + t;
        row = g >> 3; col = ((g ^ row) & 7) << 3;
        __builtin_amdgcn_global_load_lds(
          (const GLOBAL_AS void*)(Ag0 + (long)row*256 + kt*64 + col),
          (LDS_AS void*)(As + g*8), 16, 0, 0);
      }
    }
    #pragma unroll
    for (int i=0;i<2;i++){
      int g = i*512 + t;
      int row = g >> 3, col = ((g ^ row) & 7) << 3;
      __builtin_amdgcn_global_load_lds(
        (const GLOBAL_AS void*)(Bg0 + (long)row*256 + kt*64 + col),
        (LDS_AS void*)(Bs + g*8), 16, 0, 0);
    }
    __syncthreads();
    #pragma unroll
    for (int kk=0; kk<2; ++kk){
      s8v af[3], bfr[2];
      int ch = kk*4 + (lane>>4);
      #pragma unroll
      for (int mi=0;mi<3;mi++){
        int row = wr*48 + mi*16 + (lane&15);
        af[mi] = *(const s8v*)(As + row*64 + ((ch ^ (row&7))<<3));
      }
      #pragma unroll
      for (int ni=0;ni<2;ni++){
        int row = wc*32 + ni*16 + (lane&15);
        bfr[ni] = *(const s8v*)(Bs + row*64 + ((ch ^ (row&7))<<3));
      }
      #pragma unroll
      for (int mi=0;mi<3;mi++){
        #pragma unroll
        for (int ni=0;ni<2;ni++)
          acc[mi][ni] = __builtin_amdgcn_mfma_f32_16x16x32_bf16(af[mi], bfr[ni], acc[mi][ni], 0,0,0);
      }
    }
    __syncthreads();
  }

  // q|k -> LDS pre-scaled by log2e (softplus in log2 domain downstream)
  uint16_t* qs = AB;
  #pragma unroll
  for (int mi=0;mi<3;mi++){
    #pragma unroll
    for (int ni=0;ni<2;ni++){
      int col = wc*32 + ni*16 + (lane & 15);
      int ch = col >> 3;
      #pragma unroll
      for (int r2=0;r2<4;r2++){
        int row = wr*48 + mi*16 + (lane>>4)*4 + r2;
        int pch = (ch & 8) | ((ch ^ row) & 7);
        qs[row*128 + pch*8 + (col & 7)] = f2b(acc[mi][ni][r2] * 1.44269504f);
      }
    }
  }
  __syncthreads();

  float aln2[8];
  {
    int ln2i = t & 7;
    #pragma unroll
    for (int u=0;u<8;u++)
      aln2[u] = awf[ln2i*8 + u] * 0.69314718056f;
  }
  int ln = t & 7;
  for (int e0 = t >> 3; e0 < E; e0 += 64){
    int ns = esrc[e0], nd = edst[e0];
    const uint16_t* qp = qs + ns*128 + ((ln ^ ns) & 7)*8;
    const uint16_t* kp = qs + nd*128 + (8 | ((ln ^ nd) & 7))*8;
    #pragma unroll
    for (int fl=0; fl<4; ++fl){
      s8v qv = *(const s8v*)(qp + fl*3072);
      s8v kv = *(const s8v*)(kp + fl*3072);
      float s = 0.f;
      #pragma unroll
      for (int u=0;u<8;u++){
        float xv = b2f((uint16_t)qv[u]) + b2f((uint16_t)kv[u]);   // already *log2e
        float e2 = __builtin_amdgcn_exp2f(xv);
        float lg = __builtin_amdgcn_logf(1.f + e2);
        s = lg * aln2[u] + s;
      }
      s += __shfl_xor(s, 1, 64);
      s += __shfl_xor(s, 2, 64);
      s += __shfl_xor(s, 4, 64);
      if (ln == 0)
        sexg[((long)mp*4 + fl)*(E*NH) + e0*NH + h] = s;
    }
  }
}

// ---------------- gat: softmax + aggregate + residual + LN -------------------
template<int E>
__global__ __launch_bounds__(256) void gat_kernel(
    const uint16_t* __restrict__ vg, const uint16_t* __restrict__ xc,
    const int* __restrict__ edges, const float* __restrict__ sexg,
    const int* __restrict__ elg,
    const uint16_t* __restrict__ gw, const uint16_t* __restrict__ bw,
    uint16_t* __restrict__ xc_out, uint16_t* __restrict__ y,
    int ycol, int graph)
{
  __shared__ uint16_t v2s[JC*NH*32];
  __shared__ float sexs[EMAX*NH];
  __shared__ float smax[NH];
  __shared__ int edst[EMAX];
  __shared__ uint16_t glb[2*CH];

  int f = blockIdx.x;
  int t = threadIdx.x;
  const uint16_t* vf = vg + (long)f * JC * 512;
  const int EN = E * NH;

  #pragma unroll
  for (int i=0;i<3;i++){
    int g = i*256 + t;
    int r = g >> 2, cs = g & 3;
    int c = cs ^ ((r >> 1) & 3);
    int j = r >> 3, h = r & 7;
    const uint16_t* s2 = vf + j*512 + h*64 + 32 + c*8;
    __builtin_amdgcn_global_load_lds((const GLOBAL_AS void*)s2,
        (LDS_AS void*)(v2s + g*8), 16, 0, 0);
  }
  if (t < E) edst[t] = edges[E + t];
  if (t < (EN >> 2)) ((f4v*)sexs)[t] = ((const f4v*)(sexg + (long)f*EN))[t];
  glb[t] = gw[t]; glb[256 + t] = bw[t];
  __syncthreads();

  if (t < 64){
    int h = t & 7;
    float m = -3.4e38f;
    for (int e = t >> 3; e < E; e += 8) m = fmaxf(m, sexs[e*8 + h]);
    m = fmaxf(m, __shfl_xor(m, 8, 64));
    m = fmaxf(m, __shfl_xor(m, 16, 64));
    m = fmaxf(m, __shfl_xor(m, 32, 64));
    if (t < 8) smax[t] = m;
  }
  __syncthreads();

  if (t < JC*NH){
    int j = t >> 3, h = t & 7;
    int deg = elg[graph*24 + j];
    const int* lst = elg + 48 + (graph*24 + j)*8;
    float mh = smax[h];
    float ex[8];
    float sig = 1e-10f;
    int el[8];
    #pragma unroll
    for (int i=0;i<8;i++){
      float v = 0.f; int e = 0;
      if (i < deg){ e = lst[i]; v = __builtin_amdgcn_exp2f((sexs[e*8+h] - mh) * 1.44269504f); }
      el[i] = e; ex[i] = v; sig += v;
    }
    float inv = 1.f / sig;
    float acc[32];
    #pragma unroll
    for (int d=0;d<32;d++) acc[d] = 0.f;
    #pragma unroll
    for (int i=0;i<8;i++){
      if (i < deg){
        float wgt = ex[i] * inv;
        int r = edst[el[i]]*8 + h;
        int sw = (r >> 1) & 3;
        #pragma unroll
        for (int c=0;c<4;c++){
          s8v v = *(const s8v*)(v2s + r*32 + (c ^ sw)*8);
          #pragma unroll
          for (int u=0;u<8;u++) acc[c*8+u] += wgt * b2f((uint16_t)v[u]);
        }
      }
    }

    const uint16_t* v1p = vf + j*512 + h*64;
    const uint16_t* xp = xc + (long)f*JC*CH + t*32;
    float pre[32]; float sum = 0.f, sq = 0.f;
    #pragma unroll
    for (int c=0;c<4;c++){
      s8v v1 = *(const s8v*)(v1p + c*8);
      s8v xv = *(const s8v*)(xp + c*8);
      #pragma unroll
      for (int u=0;u<8;u++){
        float p = b2f((uint16_t)xv[u]) + 0.2f*b2f((uint16_t)v1[u]) + 0.8f*acc[c*8+u];
        pre[c*8+u] = p; sum += p; sq += p*p;
      }
    }
    #pragma unroll
    for (int m=1;m<8;m<<=1){ sum += __shfl_xor(sum, m, 64); sq += __shfl_xor(sq, m, 64); }
    float mean = sum * (1.f/256.f);
    float var = sq * (1.f/256.f) - mean*mean;
    float rstd = rsqrtf(var + 1e-5f);
    uint16_t* xo = xc_out + (long)f*JC*CH + t*32;
    uint16_t* yo = (j < 17) ? (y + (long)(f*17 + j)*K2 + ycol + h*32) : (uint16_t*)0;
    #pragma unroll
    for (int d0=0; d0<32; d0+=8){
      s8v ov;
      #pragma unroll
      for (int u=0;u<8;u++){
        int c = h*32 + d0 + u;
        float val = (pre[d0+u]-mean)*rstd*b2f(glb[c]) + b2f(glb[256+c]);
        ov[u] = (short)f2b(val);
      }
      *(s8v*)(xo + d0) = ov;
      if (yo) *(s8v*)(yo + d0) = ov;
    }
  }
}

// ---------------- final GEMM + bias + LN fused (writes d_out directly) --------
// C[M2][256] = y[M2][1280] * pw^T; block = 128 rows, 8 waves x 16 rows each.
__global__ __launch_bounds__(512) void final_gemm_ln(
    const uint16_t* __restrict__ A, const uint16_t* __restrict__ B,
    const uint16_t* __restrict__ pb, const uint16_t* __restrict__ gp,
    const uint16_t* __restrict__ bp, const int* __restrict__ flag,
    void* __restrict__ out)
{
  __shared__ uint16_t As[128*64];     // 16 KB
  __shared__ uint16_t Bs[256*64];     // 32 KB
  __shared__ float pbf[256], gpf[256], bpf[256];

  int t = threadIdx.x;
  int lane = t & 63, w = t >> 6;

  int total = gridDim.x;              // 173
  int q = total >> 3, r = total & 7;
  int orig = blockIdx.x;
  int xcd = orig & 7, loc = orig >> 3;
  int wgid = (xcd < r ? xcd*(q+1) : r*(q+1) + (xcd-r)*q) + loc;
  long bm = (long)wgid * 128;

  if (t < 256){ pbf[t] = b2f(pb[t]); gpf[t] = b2f(gp[t]); bpf[t] = b2f(bp[t]); }

  f4v acc[16];
  #pragma unroll
  for (int nt=0;nt<16;nt++) acc[nt] = (f4v){0.f,0.f,0.f,0.f};

  for (int kt = 0; kt < 20; ++kt){
    const uint16_t* Ag = A + bm * K2 + kt*64;
    const uint16_t* Bg = B + kt*64;
    #pragma unroll
    for (int i=0;i<2;i++){
      int g = i*512 + t;               // 1024 A granules
      int row = g >> 3, col = ((g ^ row) & 7) << 3;
      __builtin_amdgcn_global_load_lds(
        (const GLOBAL_AS void*)(Ag + (long)row*K2 + col),
        (LDS_AS void*)(As + g*8), 16, 0, 0);
    }
    #pragma unroll
    for (int i=0;i<4;i++){
      int g = i*512 + t;               // 2048 B granules
      int row = g >> 3, col = ((g ^ row) & 7) << 3;
      __builtin_amdgcn_global_load_lds(
        (const GLOBAL_AS void*)(Bg + (long)row*K2 + col),
        (LDS_AS void*)(Bs + g*8), 16, 0, 0);
    }
    __syncthreads();
    #pragma unroll
    for (int kk=0; kk<2; ++kk){
      int ch = kk*4 + (lane>>4);
      int arow = w*16 + (lane&15);
      s8v af = *(const s8v*)(As + arow*64 + ((ch ^ (arow&7))<<3));
      #pragma unroll
      for (int nt=0;nt<16;nt++){
        int brow = nt*16 + (lane&15);
        s8v bf = *(const s8v*)(Bs + brow*64 + ((ch ^ (brow&7))<<3));
        acc[nt] = __builtin_amdgcn_mfma_f32_16x16x32_bf16(af, bf, acc[nt], 0,0,0);
      }
    }
    __syncthreads();
  }

  // epilogue: bias + LN per row (row fully within this wave)
  int colbase = lane & 15;
  int g4 = lane >> 4;
  int fl32 = *flag ? 0 : 1;
  #pragma unroll
  for (int r2=0; r2<4; ++r2){
    float vloc[16]; float sum = 0.f, sq = 0.f;
    #pragma unroll
    for (int nt=0;nt<16;nt++){
      float v = acc[nt][r2] + pbf[nt*16 + colbase];
      vloc[nt] = v; sum += v; sq += v*v;
    }
    sum += __shfl_xor(sum, 1, 64); sq += __shfl_xor(sq, 1, 64);
    sum += __shfl_xor(sum, 2, 64); sq += __shfl_xor(sq, 2, 64);
    sum += __shfl_xor(sum, 4, 64); sq += __shfl_xor(sq, 4, 64);
    sum += __shfl_xor(sum, 8, 64); sq += __shfl_xor(sq, 8, 64);
    float mean = sum * (1.f/256.f);
    float var = sq * (1.f/256.f) - mean*mean;
    float rstd = rsqrtf(var + 1e-5f);
    long row = bm + w*16 + g4*4 + r2;
    if (row < MREAL){
      #pragma unroll
      for (int nt=0;nt<16;nt++){
        int col = nt*16 + colbase;
        float o = (vloc[nt]-mean)*rstd*gpf[col] + bpf[col];
        if (fl32) ((float*)out)[row*256 + col] = o;
        else ((uint16_t*)out)[row*256 + col] = f2b(o);
      }
    }
  }
}

// ---------------- launch ------------------------------------------------------
extern "C" void kernel_launch(void* const* d_in, const int* in_sizes, int n_in,
                              void* d_out, int out_size, void* d_ws, size_t ws_size,
                              hipStream_t stream){
  const int* eskel = (const int*)d_in[21];
  const int* ecay  = (const int*)d_in[22];

  char* ws = (char*)d_ws;
  const size_t QKV_B  = (size_t)M1 * N1 * 2;
  const size_t XC_B   = (size_t)M1 * CH * 2;
  const size_t Y_B    = (size_t)M2 * K2 * 2;
  const size_t ARENA_OFF = QKV_B + 2*XC_B + Y_B;
  const size_t ARENA_B = 7543808L * 2;
  uint16_t* vout = (uint16_t*)ws;
  uint16_t* xcA = (uint16_t*)(ws + QKV_B);
  uint16_t* xcB = (uint16_t*)(ws + QKV_B + XC_B);
  uint16_t* y   = (uint16_t*)(ws + QKV_B + 2*XC_B);
  uint16_t* arena = (uint16_t*)(ws + ARENA_OFF);
  int*      flag  = (int*)(ws + ARENA_OFF + ARENA_B);
  int*      elg   = flag + 16;
  uint16_t* wv    = (uint16_t*)(ws + ARENA_OFF + ARENA_B + 4096);
  float*    sexg  = (float*)arena;

  const uint16_t* x_bf = arena;
  const uint16_t* wq[4] = {arena + 5640192, arena + 6033984, arena + 6427776, arena + 6821568};
  const uint16_t* aw[4] = {arena + 6033408, arena + 6427200, arena + 6820992, arena + 7214784};
  const uint16_t* gg[4] = {arena + 6033472, arena + 6427264, arena + 6821056, arena + 7214848};
  const uint16_t* bb[4] = {arena + 6033728, arena + 6427520, arena + 6821312, arena + 7215104};
  const uint16_t* pw = arena + 7215360;
  const uint16_t* pb = arena + 7543040;
  const uint16_t* gp = arena + 7543296;
  const uint16_t* bp = arena + 7543552;

  detect_kernel<<<1, 256, 0, stream>>>((const uint16_t*)d_in[0], flag);

  Ptrs ptrs;
  for (int i = 0; i < 21; i++) ptrs.p[i] = d_in[i];
  convert_kernel<<<3684, 256, 0, stream>>>(ptrs, flag, arena);

  prep_kernel<<<53696, 256, 0, stream>>>(x_bf, xcA, y);
  build_elist<<<1, 64, 0, stream>>>(eskel, ecay, elg);

  WPtrs wp = {{wq[0], wq[1], wq[2], wq[3]}};
  wv_copy<<<256, 256, 0, stream>>>(wp, wv);

  uint16_t* xcs[2] = {xcA, xcB};
  for (int L = 0; L < 4; ++L){
    const int* ed = (L & 1) ? ecay : eskel;
    if (L & 1) qk_logit<120><<<2592, 512, 0, stream>>>(xcs[L & 1], wq[L], aw[L], ed, sexg);
    else       qk_logit<49> <<<2592, 512, 0, stream>>>(xcs[L & 1], wq[L], aw[L], ed, sexg);
    gemm_bt<0><<<972, 256, 0, stream>>>(xcs[L & 1], wv + (long)L*512*256, vout,
                                        M1, 512, K1, 4);
    if (L & 1) gat_kernel<120><<<F_FRAMES, 256, 0, stream>>>(vout, xcs[L & 1], ed, sexg, elg,
                                             gg[L], bb[L], xcs[(L + 1) & 1], y, (L + 1) * 256, 1);
    else       gat_kernel<49> <<<F_FRAMES, 256, 0, stream>>>(vout, xcs[L & 1], ed, sexg, elg,
                                             gg[L], bb[L], xcs[(L + 1) & 1], y, (L + 1) * 256, 0);
  }
  final_gemm_ln<<<173, 512, 0, stream>>>(y, pw, pb, gp, bp, flag, d_out);
}

// Round 14
// 379.707 us; speedup vs baseline: 1.2856x; 1.0606x over previous
//
#include <hip/hip_runtime.h>
#include <stdint.h>

#define F_FRAMES 1296
#define JC 24
#define CH 256
#define NH 8
#define EMAX 120
#define M1 31104
#define N1 1536
#define K1 256
#define M2 22144
#define MREAL 22032
#define K2 1280
#define N2 256

typedef __attribute__((ext_vector_type(8))) short s8v;
typedef __attribute__((ext_vector_type(4))) float f4v;

#define GLOBAL_AS __attribute__((address_space(1)))
#define LDS_AS __attribute__((address_space(3)))

__device__ __forceinline__ float b2f(uint16_t u){
  union { float f; uint32_t u; } v; v.u = ((uint32_t)u) << 16; return v.f;
}
__device__ __forceinline__ uint16_t f2b(float f){
  union { float f; uint32_t u; } v; v.f = f;
  uint32_t u = v.u;
  uint32_t r = (u + 0x7fffu + ((u >> 16) & 1u)) >> 16;
  return (uint16_t)r;
}

struct Ptrs { const void* p[21]; };

__constant__ int c_off[22] = {
  0, 5640192, 6033408, 6033472, 6033728, 6033984, 6427200, 6427264, 6427520,
  6427776, 6820992, 6821056, 6821312, 6821568, 7214784, 7214848, 7215104,
  7215360, 7543040, 7543296, 7543552, 7543808};

__device__ __forceinline__ s8v load8(const void* base, long idx, bool isbf){
  if (isbf) return *(const s8v*)((const uint16_t*)base + idx);
  const float* s = (const float*)base + idx;
  f4v a = *(const f4v*)s;
  f4v b = *(const f4v*)(s + 4);
  s8v o;
  #pragma unroll
  for (int u = 0; u < 4; u++){ o[u] = (short)f2b(a[u]); o[4+u] = (short)f2b(b[u]); }
  return o;
}

// ---------------- mega_prep: flag-inline convert + xc0 + y + pad + wv + elist --
#define NB_XC0 3888
#define NB_YCP 2754
#define NB_PAD 70
#define NB_WCV 930
#define NB_WV  256
#define MP_GRID (NB_XC0 + NB_YCP + NB_PAD + NB_WCV + NB_WV + 1)   // 7899

__global__ __launch_bounds__(256) void mega_prep(Ptrs ptrs,
        const int* __restrict__ eskel, const int* __restrict__ ecay,
        uint16_t* __restrict__ xc0, uint16_t* __restrict__ y,
        uint16_t* __restrict__ arena, uint16_t* __restrict__ wv,
        int* __restrict__ elg){
  __shared__ int cnt;
  int t = threadIdx.x;
  if (t == 0) cnt = 0;
  __syncthreads();
  const uint16_t* xr = (const uint16_t*)ptrs.p[0];
  int good = 0;
  #pragma unroll
  for (int i = 0; i < 2; i++){
    uint16_t v = xr[i*256 + t];
    int e = (v >> 7) & 0xFF;
    good += (e >= 115 && e <= 131) ? 1 : 0;
  }
  atomicAdd(&cnt, good);
  __syncthreads();
  bool isbf = cnt >= 400;

  int b = blockIdx.x;
  if (b < NB_XC0){
    int g = b*256 + t;                       // granule of 8 elems
    int row = g >> 5; int col = (g & 31) << 3;
    int f = row / 24; int j = row - f*24;
    s8v v = (s8v){0,0,0,0,0,0,0,0};
    if (j < 17) v = load8(ptrs.p[0], ((long)(f*17 + j))*256 + col, isbf);
    *(s8v*)(xc0 + (long)row*256 + col) = v;
    return;
  }
  b -= NB_XC0;
  if (b < NB_YCP){
    int g = b*256 + t;
    int row = g >> 5; int col = (g & 31) << 3;
    s8v v = load8(ptrs.p[0], (long)row*256 + col, isbf);
    *(s8v*)(y + (long)row*1280 + col) = v;
    return;
  }
  b -= NB_YCP;
  if (b < NB_PAD){
    int g = b*256 + t;
    int row = MREAL + g / 160; int col = (g % 160) << 3;
    *(s8v*)(y + (long)row*1280 + col) = (s8v){0,0,0,0,0,0,0,0};
    return;
  }
  b -= NB_PAD;
  if (b < NB_WCV){
    long idx = 5640192L + ((long)b*256 + t)*8;
    if (idx < 7543808L){
      int seg = 1;
      while (c_off[seg + 1] <= idx) seg++;
      long loc = idx - c_off[seg];
      *(s8v*)(arena + idx) = load8(ptrs.p[seg], loc, isbf);
    }
    return;
  }
  b -= NB_WCV;
  if (b < NB_WV){
    int g = b*256 + t;
    int L = g >> 14;
    int loc = g & 16383;
    int row = loc >> 5;
    int col = (loc & 31) * 8;
    int wrow = (row >> 6) * 192 + 128 + (row & 63);
    *(s8v*)(wv + ((long)L*512 + row)*256 + col) =
        load8(ptrs.p[1 + 4*L], (long)wrow*256 + col, isbf);
    return;
  }
  // elist block
  if (t < 64){
    int g = t >> 5, j = t & 31;
    if (j < 24){
      const int* ed = g ? ecay : eskel;
      int E = g ? 120 : 49;
      int c = 0;
      for (int e = 0; e < E; e++)
        if (ed[e] == j){ elg[48 + (g*24 + j)*8 + c] = e; c++; }
      elg[g*24 + j] = c;
    }
  }
}

// ---------------- vgemm: vout[M1][512] = xc * wv^T, 64x128 tile, high occ -----
__global__ __launch_bounds__(256) void vgemm(const uint16_t* __restrict__ A,
        const uint16_t* __restrict__ B, uint16_t* __restrict__ C){
  __shared__ uint16_t As[64*64];
  __shared__ uint16_t Bs[128*64];
  int t = threadIdx.x;
  int lane = t & 63, w = t >> 6;
  int wr = (w >> 1) * 32, wc = (w & 1) * 64;

  int orig = blockIdx.x;                 // 1944 = 8*243
  int wgid = (orig & 7) * 243 + (orig >> 3);
  long bm = (long)(wgid >> 2) * 64;
  long bn = (long)(wgid & 3) * 128;

  f4v acc[2][4];
  #pragma unroll
  for (int i=0;i<2;i++){
    #pragma unroll
    for (int jq=0;jq<4;jq++) acc[i][jq] = (f4v){0.f,0.f,0.f,0.f};
  }
  for (int kt = 0; kt < 4; ++kt){
    const uint16_t* Ag = A + bm * 256 + kt*64;
    const uint16_t* Bg = B + bn * 256 + kt*64;
    #pragma unroll
    for (int i=0;i<2;i++){
      int g = i*256 + t;
      int row = g >> 3, col = ((g ^ row) & 7) << 3;
      __builtin_amdgcn_global_load_lds(
        (const GLOBAL_AS void*)(Ag + (long)row*256 + col),
        (LDS_AS void*)(As + g*8), 16, 0, 0);
    }
    #pragma unroll
    for (int i=0;i<4;i++){
      int g = i*256 + t;
      int row = g >> 3, col = ((g ^ row) & 7) << 3;
      __builtin_amdgcn_global_load_lds(
        (const GLOBAL_AS void*)(Bg + (long)row*256 + col),
        (LDS_AS void*)(Bs + g*8), 16, 0, 0);
    }
    __syncthreads();
    #pragma unroll
    for (int kk=0; kk<2; ++kk){
      s8v af[2], bfr[4];
      int ch = kk*4 + (lane>>4);
      #pragma unroll
      for (int mi=0;mi<2;mi++){
        int row = wr + mi*16 + (lane&15);
        af[mi] = *(const s8v*)(As + row*64 + ((ch ^ (row&7))<<3));
      }
      #pragma unroll
      for (int ni=0;ni<4;ni++){
        int row = wc + ni*16 + (lane&15);
        bfr[ni] = *(const s8v*)(Bs + row*64 + ((ch ^ (row&7))<<3));
      }
      #pragma unroll
      for (int mi=0;mi<2;mi++){
        #pragma unroll
        for (int ni=0;ni<4;ni++)
          acc[mi][ni] = __builtin_amdgcn_mfma_f32_16x16x32_bf16(af[mi], bfr[ni], acc[mi][ni], 0,0,0);
      }
    }
    __syncthreads();
  }
  #pragma unroll
  for (int mi=0;mi<2;mi++){
    #pragma unroll
    for (int ni=0;ni<4;ni++){
      long col = bn + wc + ni*16 + (lane & 15);
      #pragma unroll
      for (int r2=0;r2<4;r2++){
        long row = bm + wr + mi*16 + (lane>>4)*4 + r2;
        C[row*512 + col] = f2b(acc[mi][ni][r2]);
      }
    }
  }
}

// ---------------- qk GEMM + fused logits (proven) -----------------------------
template<int E>
__global__ __launch_bounds__(512) void qk_logit(
    const uint16_t* __restrict__ xc_in, const uint16_t* __restrict__ W,
    const uint16_t* __restrict__ aw, const int* __restrict__ edges,
    float* __restrict__ sexg)
{
  __shared__ uint16_t AB[14336];
  __shared__ float awf[64];
  __shared__ int esrc[EMAX], edst[EMAX];

  int t = threadIdx.x;
  int lane = t & 63, w = t >> 6;
  int wr = w >> 2, wc = w & 3;

  int orig = blockIdx.x;
  int wgid = (orig & 7) * 324 + (orig >> 3);
  int mp = wgid >> 3;
  int h  = wgid & 7;

  if (t < E){ esrc[t] = edges[t]; edst[t] = edges[E+t]; }
  if (t >= 128 && t < 192) awf[t-128] = b2f(aw[t-128]);

  uint16_t* As = AB;
  uint16_t* Bs = AB + 6144;
  const uint16_t* Ag0 = xc_in + (long)mp*96*256;
  const uint16_t* Bg0 = W + (long)h*192*256;

  f4v acc[3][2];
  #pragma unroll
  for (int i=0;i<3;i++){
    acc[i][0] = (f4v){0.f,0.f,0.f,0.f};
    acc[i][1] = (f4v){0.f,0.f,0.f,0.f};
  }

  for (int kt = 0; kt < 4; ++kt){
    {
      int g = t;
      int row = g >> 3, col = ((g ^ row) & 7) << 3;
      __builtin_amdgcn_global_load_lds(
        (const GLOBAL_AS void*)(Ag0 + (long)row*256 + kt*64 + col),
        (LDS_AS void*)(As + g*8), 16, 0, 0);
      if (t < 256){
        g = 512 + t;
        row = g >> 3; col = ((g ^ row) & 7) << 3;
        __builtin_amdgcn_global_load_lds(
          (const GLOBAL_AS void*)(Ag0 + (long)row*256 + kt*64 + col),
          (LDS_AS void*)(As + g*8), 16, 0, 0);
      }
    }
    #pragma unroll
    for (int i=0;i<2;i++){
      int g = i*512 + t;
      int row = g >> 3, col = ((g ^ row) & 7) << 3;
      __builtin_amdgcn_global_load_lds(
        (const GLOBAL_AS void*)(Bg0 + (long)row*256 + kt*64 + col),
        (LDS_AS void*)(Bs + g*8), 16, 0, 0);
    }
    __syncthreads();
    #pragma unroll
    for (int kk=0; kk<2; ++kk){
      s8v af[3], bfr[2];
      int ch = kk*4 + (lane>>4);
      #pragma unroll
      for (int mi=0;mi<3;mi++){
        int row = wr*48 + mi*16 + (lane&15);
        af[mi] = *(const s8v*)(As + row*64 + ((ch ^ (row&7))<<3));
      }
      #pragma unroll
      for (int ni=0;ni<2;ni++){
        int row = wc*32 + ni*16 + (lane&15);
        bfr[ni] = *(const s8v*)(Bs + row*64 + ((ch ^ (row&7))<<3));
      }
      #pragma unroll
      for (int mi=0;mi<3;mi++){
        #pragma unroll
        for (int ni=0;ni<2;ni++)
          acc[mi][ni] = __builtin_amdgcn_mfma_f32_16x16x32_bf16(af[mi], bfr[ni], acc[mi][ni], 0,0,0);
      }
    }
    __syncthreads();
  }

  uint16_t* qs = AB;
  #pragma unroll
  for (int mi=0;mi<3;mi++){
    #pragma unroll
    for (int ni=0;ni<2;ni++){
      int col = wc*32 + ni*16 + (lane & 15);
      int ch = col >> 3;
      #pragma unroll
      for (int r2=0;r2<4;r2++){
        int row = wr*48 + mi*16 + (lane>>4)*4 + r2;
        int pch = (ch & 8) | ((ch ^ row) & 7);
        qs[row*128 + pch*8 + (col & 7)] = f2b(acc[mi][ni][r2] * 1.44269504f);
      }
    }
  }
  __syncthreads();

  float aln2[8];
  {
    int ln2i = t & 7;
    #pragma unroll
    for (int u=0;u<8;u++)
      aln2[u] = awf[ln2i*8 + u] * 0.69314718056f;
  }
  int ln = t & 7;
  for (int e0 = t >> 3; e0 < E; e0 += 64){
    int ns = esrc[e0], nd = edst[e0];
    const uint16_t* qp = qs + ns*128 + ((ln ^ ns) & 7)*8;
    const uint16_t* kp = qs + nd*128 + (8 | ((ln ^ nd) & 7))*8;
    #pragma unroll
    for (int fl=0; fl<4; ++fl){
      s8v qv = *(const s8v*)(qp + fl*3072);
      s8v kv = *(const s8v*)(kp + fl*3072);
      float s = 0.f;
      #pragma unroll
      for (int u=0;u<8;u++){
        float xv = b2f((uint16_t)qv[u]) + b2f((uint16_t)kv[u]);   // already *log2e
        float e2 = __builtin_amdgcn_exp2f(xv);
        float lg = __builtin_amdgcn_logf(1.f + e2);
        s = lg * aln2[u] + s;
      }
      s += __shfl_xor(s, 1, 64);
      s += __shfl_xor(s, 2, 64);
      s += __shfl_xor(s, 4, 64);
      if (ln == 0)
        sexg[((long)mp*4 + fl)*(E*NH) + e0*NH + h] = s;
    }
  }
}

// ---------------- gat: softmax + aggregate + residual + LN (proven) -----------
template<int E>
__global__ __launch_bounds__(256) void gat_kernel(
    const uint16_t* __restrict__ vg, const uint16_t* __restrict__ xc,
    const int* __restrict__ edges, const float* __restrict__ sexg,
    const int* __restrict__ elg,
    const uint16_t* __restrict__ gw, const uint16_t* __restrict__ bw,
    uint16_t* __restrict__ xc_out, uint16_t* __restrict__ y,
    int ycol, int graph)
{
  __shared__ uint16_t v2s[JC*NH*32];
  __shared__ float sexs[EMAX*NH];
  __shared__ float smax[NH];
  __shared__ int edst[EMAX];
  __shared__ uint16_t glb[2*CH];

  int f = blockIdx.x;
  int t = threadIdx.x;
  const uint16_t* vf = vg + (long)f * JC * 512;
  const int EN = E * NH;

  #pragma unroll
  for (int i=0;i<3;i++){
    int g = i*256 + t;
    int r = g >> 2, cs = g & 3;
    int c = cs ^ ((r >> 1) & 3);
    int j = r >> 3, h = r & 7;
    const uint16_t* s2 = vf + j*512 + h*64 + 32 + c*8;
    __builtin_amdgcn_global_load_lds((const GLOBAL_AS void*)s2,
        (LDS_AS void*)(v2s + g*8), 16, 0, 0);
  }
  if (t < E) edst[t] = edges[E + t];
  if (t < (EN >> 2)) ((f4v*)sexs)[t] = ((const f4v*)(sexg + (long)f*EN))[t];
  glb[t] = gw[t]; glb[256 + t] = bw[t];
  __syncthreads();

  if (t < 64){
    int h = t & 7;
    float m = -3.4e38f;
    for (int e = t >> 3; e < E; e += 8) m = fmaxf(m, sexs[e*8 + h]);
    m = fmaxf(m, __shfl_xor(m, 8, 64));
    m = fmaxf(m, __shfl_xor(m, 16, 64));
    m = fmaxf(m, __shfl_xor(m, 32, 64));
    if (t < 8) smax[t] = m;
  }
  __syncthreads();

  if (t < JC*NH){
    int j = t >> 3, h = t & 7;
    int deg = elg[graph*24 + j];
    const int* lst = elg + 48 + (graph*24 + j)*8;
    float mh = smax[h];
    float ex[8];
    float sig = 1e-10f;
    int el[8];
    #pragma unroll
    for (int i=0;i<8;i++){
      float v = 0.f; int e = 0;
      if (i < deg){ e = lst[i]; v = __builtin_amdgcn_exp2f((sexs[e*8+h] - mh) * 1.44269504f); }
      el[i] = e; ex[i] = v; sig += v;
    }
    float inv = 1.f / sig;
    float acc[32];
    #pragma unroll
    for (int d=0;d<32;d++) acc[d] = 0.f;
    #pragma unroll
    for (int i=0;i<8;i++){
      if (i < deg){
        float wgt = ex[i] * inv;
        int r = edst[el[i]]*8 + h;
        int sw = (r >> 1) & 3;
        #pragma unroll
        for (int c=0;c<4;c++){
          s8v v = *(const s8v*)(v2s + r*32 + (c ^ sw)*8);
          #pragma unroll
          for (int u=0;u<8;u++) acc[c*8+u] += wgt * b2f((uint16_t)v[u]);
        }
      }
    }

    const uint16_t* v1p = vf + j*512 + h*64;
    const uint16_t* xp = xc + (long)f*JC*CH + t*32;
    float pre[32]; float sum = 0.f, sq = 0.f;
    #pragma unroll
    for (int c=0;c<4;c++){
      s8v v1 = *(const s8v*)(v1p + c*8);
      s8v xv = *(const s8v*)(xp + c*8);
      #pragma unroll
      for (int u=0;u<8;u++){
        float p = b2f((uint16_t)xv[u]) + 0.2f*b2f((uint16_t)v1[u]) + 0.8f*acc[c*8+u];
        pre[c*8+u] = p; sum += p; sq += p*p;
      }
    }
    #pragma unroll
    for (int m=1;m<8;m<<=1){ sum += __shfl_xor(sum, m, 64); sq += __shfl_xor(sq, m, 64); }
    float mean = sum * (1.f/256.f);
    float var = sq * (1.f/256.f) - mean*mean;
    float rstd = rsqrtf(var + 1e-5f);
    uint16_t* xo = xc_out + (long)f*JC*CH + t*32;
    uint16_t* yo = (j < 17) ? (y + (long)(f*17 + j)*K2 + ycol + h*32) : (uint16_t*)0;
    #pragma unroll
    for (int d0=0; d0<32; d0+=8){
      s8v ov;
      #pragma unroll
      for (int u=0;u<8;u++){
        int c = h*32 + d0 + u;
        float val = (pre[d0+u]-mean)*rstd*b2f(glb[c]) + b2f(glb[256+c]);
        ov[u] = (short)f2b(val);
      }
      *(s8v*)(xo + d0) = ov;
      if (yo) *(s8v*)(yo + d0) = ov;
    }
  }
}

// ---------------- final GEMM + bias + LN, dtype detected inline ---------------
__global__ __launch_bounds__(512) void final_gemm_ln(
    const uint16_t* __restrict__ A, const uint16_t* __restrict__ B,
    const uint16_t* __restrict__ pb, const uint16_t* __restrict__ gp,
    const uint16_t* __restrict__ bp, const uint16_t* __restrict__ xraw,
    void* __restrict__ out)
{
  __shared__ uint16_t As[128*64];
  __shared__ uint16_t Bs[256*64];
  __shared__ float pbf[256], gpf[256], bpf[256];
  __shared__ int cnt;

  int t = threadIdx.x;
  int lane = t & 63, w = t >> 6;
  if (t == 0) cnt = 0;
  __syncthreads();
  {
    uint16_t v = xraw[t];
    int e = (v >> 7) & 0xFF;
    if (e >= 115 && e <= 131) atomicAdd(&cnt, 1);
  }
  if (t < 256){ pbf[t] = b2f(pb[t]); gpf[t] = b2f(gp[t]); bpf[t] = b2f(bp[t]); }
  __syncthreads();
  int fl32 = (cnt >= 400) ? 0 : 1;

  int total = gridDim.x;              // 173
  int q = total >> 3, r = total & 7;
  int orig = blockIdx.x;
  int xcd = orig & 7, loc = orig >> 3;
  int wgid = (xcd < r ? xcd*(q+1) : r*(q+1) + (xcd-r)*q) + loc;
  long bm = (long)wgid * 128;

  f4v acc[16];
  #pragma unroll
  for (int nt=0;nt<16;nt++) acc[nt] = (f4v){0.f,0.f,0.f,0.f};

  for (int kt = 0; kt < 20; ++kt){
    const uint16_t* Ag = A + bm * K2 + kt*64;
    const uint16_t* Bg = B + kt*64;
    #pragma unroll
    for (int i=0;i<2;i++){
      int g = i*512 + t;
      int row = g >> 3, col = ((g ^ row) & 7) << 3;
      __builtin_amdgcn_global_load_lds(
        (const GLOBAL_AS void*)(Ag + (long)row*K2 + col),
        (LDS_AS void*)(As + g*8), 16, 0, 0);
    }
    #pragma unroll
    for (int i=0;i<4;i++){
      int g = i*512 + t;
      int row = g >> 3, col = ((g ^ row) & 7) << 3;
      __builtin_amdgcn_global_load_lds(
        (const GLOBAL_AS void*)(Bg + (long)row*K2 + col),
        (LDS_AS void*)(Bs + g*8), 16, 0, 0);
    }
    __syncthreads();
    #pragma unroll
    for (int kk=0; kk<2; ++kk){
      int ch = kk*4 + (lane>>4);
      int arow = w*16 + (lane&15);
      s8v af = *(const s8v*)(As + arow*64 + ((ch ^ (arow&7))<<3));
      #pragma unroll
      for (int nt=0;nt<16;nt++){
        int brow = nt*16 + (lane&15);
        s8v bf = *(const s8v*)(Bs + brow*64 + ((ch ^ (brow&7))<<3));
        acc[nt] = __builtin_amdgcn_mfma_f32_16x16x32_bf16(af, bf, acc[nt], 0,0,0);
      }
    }
    __syncthreads();
  }

  int colbase = lane & 15;
  int g4 = lane >> 4;
  #pragma unroll
  for (int r2=0; r2<4; ++r2){
    float vloc[16]; float sum = 0.f, sq = 0.f;
    #pragma unroll
    for (int nt=0;nt<16;nt++){
      float v = acc[nt][r2] + pbf[nt*16 + colbase];
      vloc[nt] = v; sum += v; sq += v*v;
    }
    sum += __shfl_xor(sum, 1, 64); sq += __shfl_xor(sq, 1, 64);
    sum += __shfl_xor(sum, 2, 64); sq += __shfl_xor(sq, 2, 64);
    sum += __shfl_xor(sum, 4, 64); sq += __shfl_xor(sq, 4, 64);
    sum += __shfl_xor(sum, 8, 64); sq += __shfl_xor(sq, 8, 64);
    float mean = sum * (1.f/256.f);
    float var = sq * (1.f/256.f) - mean*mean;
    float rstd = rsqrtf(var + 1e-5f);
    long row = bm + w*16 + g4*4 + r2;
    if (row < MREAL){
      #pragma unroll
      for (int nt=0;nt<16;nt++){
        int col = nt*16 + colbase;
        float o = (vloc[nt]-mean)*rstd*gpf[col] + bpf[col];
        if (fl32) ((float*)out)[row*256 + col] = o;
        else ((uint16_t*)out)[row*256 + col] = f2b(o);
      }
    }
  }
}

// ---------------- launch ------------------------------------------------------
extern "C" void kernel_launch(void* const* d_in, const int* in_sizes, int n_in,
                              void* d_out, int out_size, void* d_ws, size_t ws_size,
                              hipStream_t stream){
  const int* eskel = (const int*)d_in[21];
  const int* ecay  = (const int*)d_in[22];

  char* ws = (char*)d_ws;
  const size_t QKV_B  = (size_t)M1 * N1 * 2;
  const size_t XC_B   = (size_t)M1 * CH * 2;
  const size_t Y_B    = (size_t)M2 * K2 * 2;
  const size_t ARENA_OFF = QKV_B + 2*XC_B + Y_B;
  const size_t ARENA_B = 7543808L * 2;
  uint16_t* vout = (uint16_t*)ws;
  uint16_t* xcA = (uint16_t*)(ws + QKV_B);
  uint16_t* xcB = (uint16_t*)(ws + QKV_B + XC_B);
  uint16_t* y   = (uint16_t*)(ws + QKV_B + 2*XC_B);
  uint16_t* arena = (uint16_t*)(ws + ARENA_OFF);
  int*      elg   = (int*)(ws + ARENA_OFF + ARENA_B) + 16;
  uint16_t* wv    = (uint16_t*)(ws + ARENA_OFF + ARENA_B + 4096);
  float*    sexg  = (float*)arena;     // overlays dead x region of arena

  const uint16_t* wq[4] = {arena + 5640192, arena + 6033984, arena + 6427776, arena + 6821568};
  const uint16_t* aw[4] = {arena + 6033408, arena + 6427200, arena + 6820992, arena + 7214784};
  const uint16_t* gg[4] = {arena + 6033472, arena + 6427264, arena + 6821056, arena + 7214848};
  const uint16_t* bb[4] = {arena + 6033728, arena + 6427520, arena + 6821312, arena + 7215104};
  const uint16_t* pw = arena + 7215360;
  const uint16_t* pb = arena + 7543040;
  const uint16_t* gp = arena + 7543296;
  const uint16_t* bp = arena + 7543552;

  Ptrs ptrs;
  for (int i = 0; i < 21; i++) ptrs.p[i] = d_in[i];
  mega_prep<<<MP_GRID, 256, 0, stream>>>(ptrs, eskel, ecay, xcA, y, arena, wv, elg);

  uint16_t* xcs[2] = {xcA, xcB};
  for (int L = 0; L < 4; ++L){
    const int* ed = (L & 1) ? ecay : eskel;
    if (L & 1) qk_logit<120><<<2592, 512, 0, stream>>>(xcs[L & 1], wq[L], aw[L], ed, sexg);
    else       qk_logit<49> <<<2592, 512, 0, stream>>>(xcs[L & 1], wq[L], aw[L], ed, sexg);
    vgemm<<<1944, 256, 0, stream>>>(xcs[L & 1], wv + (long)L*512*256, vout);
    if (L & 1) gat_kernel<120><<<F_FRAMES, 256, 0, stream>>>(vout, xcs[L & 1], ed, sexg, elg,
                                             gg[L], bb[L], xcs[(L + 1) & 1], y, (L + 1) * 256, 1);
    else       gat_kernel<49> <<<F_FRAMES, 256, 0, stream>>>(vout, xcs[L & 1], ed, sexg, elg,
                                             gg[L], bb[L], xcs[(L + 1) & 1], y, (L + 1) * 256, 0);
  }
  final_gemm_ln<<<173, 512, 0, stream>>>(y, pw, pb, gp, bp, (const uint16_t*)d_in[0], d_out);
}

// Round 15
// 353.902 us; speedup vs baseline: 1.3794x; 1.0729x over previous
//
#include <hip/hip_runtime.h>
#include <stdint.h>

#define F_FRAMES 1296
#define JC 24
#define CH 256
#define NH 8
#define EMAX 120
#define M1 31104
#define N1 1536
#define K1 256
#define M2 22144
#define MREAL 22032
#define K2 1280
#define N2 256

typedef __attribute__((ext_vector_type(8))) short s8v;
typedef __attribute__((ext_vector_type(4))) float f4v;

#define GLOBAL_AS __attribute__((address_space(1)))
#define LDS_AS __attribute__((address_space(3)))

__device__ __forceinline__ float b2f(uint16_t u){
  union { float f; uint32_t u; } v; v.u = ((uint32_t)u) << 16; return v.f;
}
__device__ __forceinline__ uint16_t f2b(float f){
  union { float f; uint32_t u; } v; v.f = f;
  uint32_t u = v.u;
  uint32_t r = (u + 0x7fffu + ((u >> 16) & 1u)) >> 16;
  return (uint16_t)r;
}

struct Ptrs { const void* p[21]; };

__constant__ int c_off[22] = {
  0, 5640192, 6033408, 6033472, 6033728, 6033984, 6427200, 6427264, 6427520,
  6427776, 6820992, 6821056, 6821312, 6821568, 7214784, 7214848, 7215104,
  7215360, 7543040, 7543296, 7543552, 7543808};

__device__ __forceinline__ s8v load8(const void* base, long idx, bool isbf){
  if (isbf) return *(const s8v*)((const uint16_t*)base + idx);
  const float* s = (const float*)base + idx;
  f4v a = *(const f4v*)s;
  f4v b = *(const f4v*)(s + 4);
  s8v o;
  #pragma unroll
  for (int u = 0; u < 4; u++){ o[u] = (short)f2b(a[u]); o[4+u] = (short)f2b(b[u]); }
  return o;
}

// ---------------- mega_prep: flag-inline convert + xc0 + y + pad + wv + elist --
#define NB_XC0 3888
#define NB_YCP 2754
#define NB_PAD 70
#define NB_WCV 930
#define NB_WV  256
#define MP_GRID (NB_XC0 + NB_YCP + NB_PAD + NB_WCV + NB_WV + 1)   // 7899

__global__ __launch_bounds__(256) void mega_prep(Ptrs ptrs,
        const int* __restrict__ eskel, const int* __restrict__ ecay,
        uint16_t* __restrict__ xc0, uint16_t* __restrict__ y,
        uint16_t* __restrict__ arena, uint16_t* __restrict__ wv,
        int* __restrict__ elg){
  __shared__ int cnt;
  int t = threadIdx.x;
  if (t == 0) cnt = 0;
  __syncthreads();
  const uint16_t* xr = (const uint16_t*)ptrs.p[0];
  int good = 0;
  #pragma unroll
  for (int i = 0; i < 2; i++){
    uint16_t v = xr[i*256 + t];
    int e = (v >> 7) & 0xFF;
    good += (e >= 115 && e <= 131) ? 1 : 0;
  }
  atomicAdd(&cnt, good);
  __syncthreads();
  bool isbf = cnt >= 400;

  int b = blockIdx.x;
  if (b < NB_XC0){
    int g = b*256 + t;
    int row = g >> 5; int col = (g & 31) << 3;
    int f = row / 24; int j = row - f*24;
    s8v v = (s8v){0,0,0,0,0,0,0,0};
    if (j < 17) v = load8(ptrs.p[0], ((long)(f*17 + j))*256 + col, isbf);
    *(s8v*)(xc0 + (long)row*256 + col) = v;
    return;
  }
  b -= NB_XC0;
  if (b < NB_YCP){
    int g = b*256 + t;
    int row = g >> 5; int col = (g & 31) << 3;
    s8v v = load8(ptrs.p[0], (long)row*256 + col, isbf);
    *(s8v*)(y + (long)row*1280 + col) = v;
    return;
  }
  b -= NB_YCP;
  if (b < NB_PAD){
    int g = b*256 + t;
    int row = MREAL + g / 160; int col = (g % 160) << 3;
    *(s8v*)(y + (long)row*1280 + col) = (s8v){0,0,0,0,0,0,0,0};
    return;
  }
  b -= NB_PAD;
  if (b < NB_WCV){
    long idx = 5640192L + ((long)b*256 + t)*8;
    if (idx < 7543808L){
      int seg = 1;
      while (c_off[seg + 1] <= idx) seg++;
      long loc = idx - c_off[seg];
      *(s8v*)(arena + idx) = load8(ptrs.p[seg], loc, isbf);
    }
    return;
  }
  b -= NB_WCV;
  if (b < NB_WV){
    int g = b*256 + t;
    int L = g >> 14;
    int loc = g & 16383;
    int row = loc >> 5;
    int col = (loc & 31) * 8;
    int wrow = (row >> 6) * 192 + 128 + (row & 63);
    *(s8v*)(wv + ((long)L*512 + row)*256 + col) =
        load8(ptrs.p[1 + 4*L], (long)wrow*256 + col, isbf);
    return;
  }
  if (t < 64){
    int g = t >> 5, j = t & 31;
    if (j < 24){
      const int* ed = g ? ecay : eskel;
      int E = g ? 120 : 49;
      int c = 0;
      for (int e = 0; e < E; e++)
        if (ed[e] == j){ elg[48 + (g*24 + j)*8 + c] = e; c++; }
      elg[g*24 + j] = c;
    }
  }
}

// ---------------- layer_qkv: qk GEMM+logits (blocks 0..2591) ||
//                  v GEMM 128x128 (blocks 2592..3563) — independent work -------
template<int E>
__global__ __launch_bounds__(512) void layer_qkv(
    const uint16_t* __restrict__ xc_in, const uint16_t* __restrict__ W,
    const uint16_t* __restrict__ aw, const int* __restrict__ edges,
    float* __restrict__ sexg, const uint16_t* __restrict__ wvL,
    uint16_t* __restrict__ vout)
{
  __shared__ __align__(16) char SH[33792];

  int t = threadIdx.x;
  int lane = t & 63, w = t >> 6;

  if (blockIdx.x < 2592){
    // ---------------- qk + logits (proven round-11 body) ----------------
    uint16_t* AB  = (uint16_t*)SH;                 // 28672 B
    float*    awf = (float*)(SH + 28672);          // 256 B
    int*      esrc = (int*)(SH + 28928);           // 480 B
    int*      edst = (int*)(SH + 29408);           // 480 B

    int wr = w >> 2, wc = w & 3;
    int orig = blockIdx.x;
    int wgid = (orig & 7) * 324 + (orig >> 3);
    int mp = wgid >> 3;
    int h  = wgid & 7;

    if (t < E){ esrc[t] = edges[t]; edst[t] = edges[E+t]; }
    if (t >= 128 && t < 192) awf[t-128] = b2f(aw[t-128]);

    uint16_t* As = AB;
    uint16_t* Bs = AB + 6144;
    const uint16_t* Ag0 = xc_in + (long)mp*96*256;
    const uint16_t* Bg0 = W + (long)h*192*256;

    f4v acc[3][2];
    #pragma unroll
    for (int i=0;i<3;i++){
      acc[i][0] = (f4v){0.f,0.f,0.f,0.f};
      acc[i][1] = (f4v){0.f,0.f,0.f,0.f};
    }

    for (int kt = 0; kt < 4; ++kt){
      {
        int g = t;
        int row = g >> 3, col = ((g ^ row) & 7) << 3;
        __builtin_amdgcn_global_load_lds(
          (const GLOBAL_AS void*)(Ag0 + (long)row*256 + kt*64 + col),
          (LDS_AS void*)(As + g*8), 16, 0, 0);
        if (t < 256){
          g = 512 + t;
          row = g >> 3; col = ((g ^ row) & 7) << 3;
          __builtin_amdgcn_global_load_lds(
            (const GLOBAL_AS void*)(Ag0 + (long)row*256 + kt*64 + col),
            (LDS_AS void*)(As + g*8), 16, 0, 0);
        }
      }
      #pragma unroll
      for (int i=0;i<2;i++){
        int g = i*512 + t;
        int row = g >> 3, col = ((g ^ row) & 7) << 3;
        __builtin_amdgcn_global_load_lds(
          (const GLOBAL_AS void*)(Bg0 + (long)row*256 + kt*64 + col),
          (LDS_AS void*)(Bs + g*8), 16, 0, 0);
      }
      __syncthreads();
      #pragma unroll
      for (int kk=0; kk<2; ++kk){
        s8v af[3], bfr[2];
        int ch = kk*4 + (lane>>4);
        #pragma unroll
        for (int mi=0;mi<3;mi++){
          int row = wr*48 + mi*16 + (lane&15);
          af[mi] = *(const s8v*)(As + row*64 + ((ch ^ (row&7))<<3));
        }
        #pragma unroll
        for (int ni=0;ni<2;ni++){
          int row = wc*32 + ni*16 + (lane&15);
          bfr[ni] = *(const s8v*)(Bs + row*64 + ((ch ^ (row&7))<<3));
        }
        #pragma unroll
        for (int mi=0;mi<3;mi++){
          #pragma unroll
          for (int ni=0;ni<2;ni++)
            acc[mi][ni] = __builtin_amdgcn_mfma_f32_16x16x32_bf16(af[mi], bfr[ni], acc[mi][ni], 0,0,0);
        }
      }
      __syncthreads();
    }

    uint16_t* qs = AB;
    #pragma unroll
    for (int mi=0;mi<3;mi++){
      #pragma unroll
      for (int ni=0;ni<2;ni++){
        int col = wc*32 + ni*16 + (lane & 15);
        int ch = col >> 3;
        #pragma unroll
        for (int r2=0;r2<4;r2++){
          int row = wr*48 + mi*16 + (lane>>4)*4 + r2;
          int pch = (ch & 8) | ((ch ^ row) & 7);
          qs[row*128 + pch*8 + (col & 7)] = f2b(acc[mi][ni][r2] * 1.44269504f);
        }
      }
    }
    __syncthreads();

    float aln2[8];
    {
      int ln2i = t & 7;
      #pragma unroll
      for (int u=0;u<8;u++)
        aln2[u] = awf[ln2i*8 + u] * 0.69314718056f;
    }
    int ln = t & 7;
    for (int e0 = t >> 3; e0 < E; e0 += 64){
      int ns = esrc[e0], nd = edst[e0];
      const uint16_t* qp = qs + ns*128 + ((ln ^ ns) & 7)*8;
      const uint16_t* kp = qs + nd*128 + (8 | ((ln ^ nd) & 7))*8;
      #pragma unroll
      for (int fl=0; fl<4; ++fl){
        s8v qv = *(const s8v*)(qp + fl*3072);
        s8v kv = *(const s8v*)(kp + fl*3072);
        float s = 0.f;
        #pragma unroll
        for (int u=0;u<8;u++){
          float xv = b2f((uint16_t)qv[u]) + b2f((uint16_t)kv[u]);
          float e2 = __builtin_amdgcn_exp2f(xv);
          float lg = __builtin_amdgcn_logf(1.f + e2);
          s = lg * aln2[u] + s;
        }
        s += __shfl_xor(s, 1, 64);
        s += __shfl_xor(s, 2, 64);
        s += __shfl_xor(s, 4, 64);
        if (ln == 0)
          sexg[((long)mp*4 + fl)*(E*NH) + e0*NH + h] = s;
      }
    }
  } else {
    // ---------------- v GEMM: vout[M1][512] = xc * wv^T, 128x128 tile ----
    uint16_t* As = (uint16_t*)SH;            // 16384 B
    uint16_t* Bs = (uint16_t*)(SH + 16384);  // 16384 B

    int vb = blockIdx.x - 2592;              // 0..971, vb&7 = actual XCD
    int xcd = vb & 7, loc = vb >> 3;
    int wgid = (xcd < 4 ? xcd*122 : 488 + (xcd-4)*121) + loc;
    long bm = (long)(wgid >> 2) * 128;
    long bn = (long)(wgid & 3) * 128;

    int wr = w >> 2, wc = w & 3;             // 2x4 wave grid, 64x32 each

    f4v acc[4][2];
    #pragma unroll
    for (int i=0;i<4;i++){
      acc[i][0] = (f4v){0.f,0.f,0.f,0.f};
      acc[i][1] = (f4v){0.f,0.f,0.f,0.f};
    }
    for (int kt = 0; kt < 4; ++kt){
      const uint16_t* Ag = xc_in + bm * 256 + kt*64;
      const uint16_t* Bg = wvL + bn * 256 + kt*64;
      #pragma unroll
      for (int i=0;i<2;i++){
        int g = i*512 + t;
        int row = g >> 3, col = ((g ^ row) & 7) << 3;
        __builtin_amdgcn_global_load_lds(
          (const GLOBAL_AS void*)(Ag + (long)row*256 + col),
          (LDS_AS void*)(As + g*8), 16, 0, 0);
      }
      #pragma unroll
      for (int i=0;i<2;i++){
        int g = i*512 + t;
        int row = g >> 3, col = ((g ^ row) & 7) << 3;
        __builtin_amdgcn_global_load_lds(
          (const GLOBAL_AS void*)(Bg + (long)row*256 + col),
          (LDS_AS void*)(Bs + g*8), 16, 0, 0);
      }
      __syncthreads();
      #pragma unroll
      for (int kk=0; kk<2; ++kk){
        s8v af[4], bfr[2];
        int ch = kk*4 + (lane>>4);
        #pragma unroll
        for (int mi=0;mi<4;mi++){
          int row = wr*64 + mi*16 + (lane&15);
          af[mi] = *(const s8v*)(As + row*64 + ((ch ^ (row&7))<<3));
        }
        #pragma unroll
        for (int ni=0;ni<2;ni++){
          int row = wc*32 + ni*16 + (lane&15);
          bfr[ni] = *(const s8v*)(Bs + row*64 + ((ch ^ (row&7))<<3));
        }
        #pragma unroll
        for (int mi=0;mi<4;mi++){
          #pragma unroll
          for (int ni=0;ni<2;ni++)
            acc[mi][ni] = __builtin_amdgcn_mfma_f32_16x16x32_bf16(af[mi], bfr[ni], acc[mi][ni], 0,0,0);
        }
      }
      __syncthreads();
    }
    #pragma unroll
    for (int mi=0;mi<4;mi++){
      #pragma unroll
      for (int ni=0;ni<2;ni++){
        long col = bn + wc*32 + ni*16 + (lane & 15);
        #pragma unroll
        for (int r2=0;r2<4;r2++){
          long row = bm + wr*64 + mi*16 + (lane>>4)*4 + r2;
          vout[row*512 + col] = f2b(acc[mi][ni][r2]);
        }
      }
    }
  }
}

// ---------------- gat: softmax + aggregate + residual + LN (proven) -----------
template<int E>
__global__ __launch_bounds__(256) void gat_kernel(
    const uint16_t* __restrict__ vg, const uint16_t* __restrict__ xc,
    const int* __restrict__ edges, const float* __restrict__ sexg,
    const int* __restrict__ elg,
    const uint16_t* __restrict__ gw, const uint16_t* __restrict__ bw,
    uint16_t* __restrict__ xc_out, uint16_t* __restrict__ y,
    int ycol, int graph)
{
  __shared__ uint16_t v2s[JC*NH*32];
  __shared__ float sexs[EMAX*NH];
  __shared__ float smax[NH];
  __shared__ int edst[EMAX];
  __shared__ uint16_t glb[2*CH];

  int f = blockIdx.x;
  int t = threadIdx.x;
  const uint16_t* vf = vg + (long)f * JC * 512;
  const int EN = E * NH;

  #pragma unroll
  for (int i=0;i<3;i++){
    int g = i*256 + t;
    int r = g >> 2, cs = g & 3;
    int c = cs ^ ((r >> 1) & 3);
    int j = r >> 3, h = r & 7;
    const uint16_t* s2 = vf + j*512 + h*64 + 32 + c*8;
    __builtin_amdgcn_global_load_lds((const GLOBAL_AS void*)s2,
        (LDS_AS void*)(v2s + g*8), 16, 0, 0);
  }
  if (t < E) edst[t] = edges[E + t];
  if (t < (EN >> 2)) ((f4v*)sexs)[t] = ((const f4v*)(sexg + (long)f*EN))[t];
  glb[t] = gw[t]; glb[256 + t] = bw[t];
  __syncthreads();

  if (t < 64){
    int h = t & 7;
    float m = -3.4e38f;
    for (int e = t >> 3; e < E; e += 8) m = fmaxf(m, sexs[e*8 + h]);
    m = fmaxf(m, __shfl_xor(m, 8, 64));
    m = fmaxf(m, __shfl_xor(m, 16, 64));
    m = fmaxf(m, __shfl_xor(m, 32, 64));
    if (t < 8) smax[t] = m;
  }
  __syncthreads();

  if (t < JC*NH){
    int j = t >> 3, h = t & 7;
    int deg = elg[graph*24 + j];
    const int* lst = elg + 48 + (graph*24 + j)*8;
    float mh = smax[h];
    float ex[8];
    float sig = 1e-10f;
    int el[8];
    #pragma unroll
    for (int i=0;i<8;i++){
      float v = 0.f; int e = 0;
      if (i < deg){ e = lst[i]; v = __builtin_amdgcn_exp2f((sexs[e*8+h] - mh) * 1.44269504f); }
      el[i] = e; ex[i] = v; sig += v;
    }
    float inv = 1.f / sig;
    float acc[32];
    #pragma unroll
    for (int d=0;d<32;d++) acc[d] = 0.f;
    #pragma unroll
    for (int i=0;i<8;i++){
      if (i < deg){
        float wgt = ex[i] * inv;
        int r = edst[el[i]]*8 + h;
        int sw = (r >> 1) & 3;
        #pragma unroll
        for (int c=0;c<4;c++){
          s8v v = *(const s8v*)(v2s + r*32 + (c ^ sw)*8);
          #pragma unroll
          for (int u=0;u<8;u++) acc[c*8+u] += wgt * b2f((uint16_t)v[u]);
        }
      }
    }

    const uint16_t* v1p = vf + j*512 + h*64;
    const uint16_t* xp = xc + (long)f*JC*CH + t*32;
    float pre[32]; float sum = 0.f, sq = 0.f;
    #pragma unroll
    for (int c=0;c<4;c++){
      s8v v1 = *(const s8v*)(v1p + c*8);
      s8v xv = *(const s8v*)(xp + c*8);
      #pragma unroll
      for (int u=0;u<8;u++){
        float p = b2f((uint16_t)xv[u]) + 0.2f*b2f((uint16_t)v1[u]) + 0.8f*acc[c*8+u];
        pre[c*8+u] = p; sum += p; sq += p*p;
      }
    }
    #pragma unroll
    for (int m=1;m<8;m<<=1){ sum += __shfl_xor(sum, m, 64); sq += __shfl_xor(sq, m, 64); }
    float mean = sum * (1.f/256.f);
    float var = sq * (1.f/256.f) - mean*mean;
    float rstd = rsqrtf(var + 1e-5f);
    uint16_t* xo = xc_out + (long)f*JC*CH + t*32;
    uint16_t* yo = (j < 17) ? (y + (long)(f*17 + j)*K2 + ycol + h*32) : (uint16_t*)0;
    #pragma unroll
    for (int d0=0; d0<32; d0+=8){
      s8v ov;
      #pragma unroll
      for (int u=0;u<8;u++){
        int c = h*32 + d0 + u;
        float val = (pre[d0+u]-mean)*rstd*b2f(glb[c]) + b2f(glb[256+c]);
        ov[u] = (short)f2b(val);
      }
      *(s8v*)(xo + d0) = ov;
      if (yo) *(s8v*)(yo + d0) = ov;
    }
  }
}

// ---------------- final GEMM + bias + LN, dtype detected inline ---------------
__global__ __launch_bounds__(512) void final_gemm_ln(
    const uint16_t* __restrict__ A, const uint16_t* __restrict__ B,
    const uint16_t* __restrict__ pb, const uint16_t* __restrict__ gp,
    const uint16_t* __restrict__ bp, const uint16_t* __restrict__ xraw,
    void* __restrict__ out)
{
  __shared__ uint16_t As[128*64];
  __shared__ uint16_t Bs[256*64];
  __shared__ float pbf[256], gpf[256], bpf[256];
  __shared__ int cnt;

  int t = threadIdx.x;
  int lane = t & 63, w = t >> 6;
  if (t == 0) cnt = 0;
  __syncthreads();
  {
    uint16_t v = xraw[t];
    int e = (v >> 7) & 0xFF;
    if (e >= 115 && e <= 131) atomicAdd(&cnt, 1);
  }
  if (t < 256){ pbf[t] = b2f(pb[t]); gpf[t] = b2f(gp[t]); bpf[t] = b2f(bp[t]); }
  __syncthreads();
  int fl32 = (cnt >= 400) ? 0 : 1;

  int total = gridDim.x;
  int q = total >> 3, r = total & 7;
  int orig = blockIdx.x;
  int xcd = orig & 7, loc = orig >> 3;
  int wgid = (xcd < r ? xcd*(q+1) : r*(q+1) + (xcd-r)*q) + loc;
  long bm = (long)wgid * 128;

  f4v acc[16];
  #pragma unroll
  for (int nt=0;nt<16;nt++) acc[nt] = (f4v){0.f,0.f,0.f,0.f};

  for (int kt = 0; kt < 20; ++kt){
    const uint16_t* Ag = A + bm * K2 + kt*64;
    const uint16_t* Bg = B + kt*64;
    #pragma unroll
    for (int i=0;i<2;i++){
      int g = i*512 + t;
      int row = g >> 3, col = ((g ^ row) & 7) << 3;
      __builtin_amdgcn_global_load_lds(
        (const GLOBAL_AS void*)(Ag + (long)row*K2 + col),
        (LDS_AS void*)(As + g*8), 16, 0, 0);
    }
    #pragma unroll
    for (int i=0;i<4;i++){
      int g = i*512 + t;
      int row = g >> 3, col = ((g ^ row) & 7) << 3;
      __builtin_amdgcn_global_load_lds(
        (const GLOBAL_AS void*)(Bg + (long)row*K2 + col),
        (LDS_AS void*)(Bs + g*8), 16, 0, 0);
    }
    __syncthreads();
    #pragma unroll
    for (int kk=0; kk<2; ++kk){
      int ch = kk*4 + (lane>>4);
      int arow = w*16 + (lane&15);
      s8v af = *(const s8v*)(As + arow*64 + ((ch ^ (arow&7))<<3));
      #pragma unroll
      for (int nt=0;nt<16;nt++){
        int brow = nt*16 + (lane&15);
        s8v bf = *(const s8v*)(Bs + brow*64 + ((ch ^ (brow&7))<<3));
        acc[nt] = __builtin_amdgcn_mfma_f32_16x16x32_bf16(af, bf, acc[nt], 0,0,0);
      }
    }
    __syncthreads();
  }

  int colbase = lane & 15;
  int g4 = lane >> 4;
  #pragma unroll
  for (int r2=0; r2<4; ++r2){
    float vloc[16]; float sum = 0.f, sq = 0.f;
    #pragma unroll
    for (int nt=0;nt<16;nt++){
      float v = acc[nt][r2] + pbf[nt*16 + colbase];
      vloc[nt] = v; sum += v; sq += v*v;
    }
    sum += __shfl_xor(sum, 1, 64); sq += __shfl_xor(sq, 1, 64);
    sum += __shfl_xor(sum, 2, 64); sq += __shfl_xor(sq, 2, 64);
    sum += __shfl_xor(sum, 4, 64); sq += __shfl_xor(sq, 4, 64);
    sum += __shfl_xor(sum, 8, 64); sq += __shfl_xor(sq, 8, 64);
    float mean = sum * (1.f/256.f);
    float var = sq * (1.f/256.f) - mean*mean;
    float rstd = rsqrtf(var + 1e-5f);
    long row = bm + w*16 + g4*4 + r2;
    if (row < MREAL){
      #pragma unroll
      for (int nt=0;nt<16;nt++){
        int col = nt*16 + colbase;
        float o = (vloc[nt]-mean)*rstd*gpf[col] + bpf[col];
        if (fl32) ((float*)out)[row*256 + col] = o;
        else ((uint16_t*)out)[row*256 + col] = f2b(o);
      }
    }
  }
}

// ---------------- launch ------------------------------------------------------
extern "C" void kernel_launch(void* const* d_in, const int* in_sizes, int n_in,
                              void* d_out, int out_size, void* d_ws, size_t ws_size,
                              hipStream_t stream){
  const int* eskel = (const int*)d_in[21];
  const int* ecay  = (const int*)d_in[22];

  char* ws = (char*)d_ws;
  const size_t QKV_B  = (size_t)M1 * N1 * 2;
  const size_t XC_B   = (size_t)M1 * CH * 2;
  const size_t Y_B    = (size_t)M2 * K2 * 2;
  const size_t ARENA_OFF = QKV_B + 2*XC_B + Y_B;
  const size_t ARENA_B = 7543808L * 2;
  uint16_t* vout = (uint16_t*)ws;
  uint16_t* xcA = (uint16_t*)(ws + QKV_B);
  uint16_t* xcB = (uint16_t*)(ws + QKV_B + XC_B);
  uint16_t* y   = (uint16_t*)(ws + QKV_B + 2*XC_B);
  uint16_t* arena = (uint16_t*)(ws + ARENA_OFF);
  int*      elg   = (int*)(ws + ARENA_OFF + ARENA_B) + 16;
  uint16_t* wv    = (uint16_t*)(ws + ARENA_OFF + ARENA_B + 4096);
  float*    sexg  = (float*)arena;

  const uint16_t* wq[4] = {arena + 5640192, arena + 6033984, arena + 6427776, arena + 6821568};
  const uint16_t* aw[4] = {arena + 6033408, arena + 6427200, arena + 6820992, arena + 7214784};
  const uint16_t* gg[4] = {arena + 6033472, arena + 6427264, arena + 6821056, arena + 7214848};
  const uint16_t* bb[4] = {arena + 6033728, arena + 6427520, arena + 6821312, arena + 7215104};
  const uint16_t* pw = arena + 7215360;
  const uint16_t* pb = arena + 7543040;
  const uint16_t* gp = arena + 7543296;
  const uint16_t* bp = arena + 7543552;

  Ptrs ptrs;
  for (int i = 0; i < 21; i++) ptrs.p[i] = d_in[i];
  mega_prep<<<MP_GRID, 256, 0, stream>>>(ptrs, eskel, ecay, xcA, y, arena, wv, elg);

  uint16_t* xcs[2] = {xcA, xcB};
  for (int L = 0; L < 4; ++L){
    const int* ed = (L & 1) ? ecay : eskel;
    if (L & 1) layer_qkv<120><<<3564, 512, 0, stream>>>(xcs[L & 1], wq[L], aw[L], ed, sexg,
                                                        wv + (long)L*512*256, vout);
    else       layer_qkv<49> <<<3564, 512, 0, stream>>>(xcs[L & 1], wq[L], aw[L], ed, sexg,
                                                        wv + (long)L*512*256, vout);
    if (L & 1) gat_kernel<120><<<F_FRAMES, 256, 0, stream>>>(vout, xcs[L & 1], ed, sexg, elg,
                                             gg[L], bb[L], xcs[(L + 1) & 1], y, (L + 1) * 256, 1);
    else       gat_kernel<49> <<<F_FRAMES, 256, 0, stream>>>(vout, xcs[L & 1], ed, sexg, elg,
                                             gg[L], bb[L], xcs[(L + 1) & 1], y, (L + 1) * 256, 0);
  }
  final_gemm_ln<<<173, 512, 0, stream>>>(y, pw, pb, gp, bp, (const uint16_t*)d_in[0], d_out);
}